// Round 8
// baseline (1928.310 us; speedup 1.0000x reference)
//
#include <hip/hip_runtime.h>
#include <stdint.h>

typedef _Float16 f16;
typedef __attribute__((ext_vector_type(4))) float floatx4;
typedef __attribute__((ext_vector_type(8))) f16   f16x8;
typedef __attribute__((ext_vector_type(4))) f16   f16x4;

#define GLD_LDS16(gp, lp)                                                                      \
  __builtin_amdgcn_global_load_lds((const __attribute__((address_space(1))) void*)(uintptr_t)(gp), \
                                   (__attribute__((address_space(3))) void*)(uintptr_t)(lp), 16, 0, 0)

// ---------------- generalized f16 MFMA GEMM: C = alpha*A@B^T (+bias)(+resid) ----------------
struct SrlOut {
  int n0;
  const float* bias;
  const float* resid;
  float* Cf; f16* Cb;
  int ldcf, ldcb, transV;
  long long sCb, sCh;
};
struct SrlGemmArgs {
  const f16* A; const f16* B;
  int M, N, K, lda, ldb;
  long long sAb, sAh, sBb, sBh;
  float alpha;
  int nOuts;
  SrlOut out[4];
};

// 64x64 no-LDS direct-fragment GEMM. r5/r6/r7 lesson: every barrier-synchronized LDS variant
// loses — the LDS READ path (32KB/K-tile, ~1540 cyc/CU at 4 blocks/CU) is 3x the MFMA work,
// and barriers serialize it with staging. Here both operands are K-contiguous per row, and the
// 16x16x32 fragment is exactly 8 contiguous f16 at row*ld + k0 + ks*32 + quad*8 — so fragments
// load DIRECTLY from global into registers: no LDS, no barriers, compiler pipelines loads
// across K-tiles freely, 16 waves/CU hide L2 latency. Register double-buffer, 128 K per iter
// (all routed K in {512,1024,2048} divide 128). Requirements: M,N % 64 == 0.
template<int MINW>
__global__ __launch_bounds__(256, MINW) void srl_gemm(SrlGemmArgs g) {
  const int tid  = threadIdx.x;
  const int wid  = tid >> 6;
  const int lane = tid & 63;

  const int gx = gridDim.x;
  const int NT = gx * gridDim.y;
  const int L  = blockIdx.y * gx + blockIdx.x;
  const int W  = ((NT & 7) == 0) ? ((L & 7) * (NT >> 3) + (L >> 3)) : L;
  const int tn = (W % gx) * 64;
  const int tm = (W / gx) * 64;

  const int wm = (wid & 1) * 32;
  const int wn = (wid >> 1) * 32;
  const int lm = lane & 15;
  const int quad = lane >> 4;

  // per-lane fragment base addresses (A row-major, B^T row-major, both K-contiguous)
  const f16* A0 = g.A + (long long)(tm + wm + lm) * g.lda + quad * 8;
  const f16* A1 = A0 + 16 * g.lda;
  const f16* B0 = g.B + (long long)(tn + wn + lm) * g.ldb + quad * 8;
  const f16* B1 = B0 + 16 * g.ldb;

  floatx4 acc[2][2];
#pragma unroll
  for (int a = 0; a < 2; ++a)
#pragma unroll
    for (int b = 0; b < 2; ++b) {
      acc[a][b][0] = 0.f; acc[a][b][1] = 0.f; acc[a][b][2] = 0.f; acc[a][b][3] = 0.f;
    }

  f16x8 aA[2][2], bA[2][2], aB[2][2], bB[2][2];

  auto ld = [&](f16x8 (&aa)[2][2], f16x8 (&bb)[2][2], int k0) {
#pragma unroll
    for (int ks = 0; ks < 2; ++ks) {
      aa[ks][0] = *(const f16x8*)(A0 + k0 + ks * 32);
      aa[ks][1] = *(const f16x8*)(A1 + k0 + ks * 32);
      bb[ks][0] = *(const f16x8*)(B0 + k0 + ks * 32);
      bb[ks][1] = *(const f16x8*)(B1 + k0 + ks * 32);
    }
  };
  auto mm = [&](f16x8 (&aa)[2][2], f16x8 (&bb)[2][2]) {
#pragma unroll
    for (int ks = 0; ks < 2; ++ks)
#pragma unroll
      for (int mi = 0; mi < 2; ++mi)
#pragma unroll
        for (int ni = 0; ni < 2; ++ni)
          acc[mi][ni] = __builtin_amdgcn_mfma_f32_16x16x32_f16(aa[ks][mi], bb[ks][ni], acc[mi][ni], 0, 0, 0);
  };

  const int nk2 = g.K >> 7;   // 128 K per iteration
  ld(aA, bA, 0);
  for (int t = 0; t < nk2; ++t) {
    const int k0 = t << 7;
    ld(aB, bB, k0 + 64);
    mm(aA, bA);
    if (t + 1 < nk2) ld(aA, bA, k0 + 128);
    mm(aB, bB);
  }

  int oi = 0;
  for (int j = 1; j < g.nOuts; ++j)
    if (tn >= g.out[j].n0) oi = j;
  const SrlOut O = g.out[oi];
#pragma unroll
  for (int mi = 0; mi < 2; ++mi) {
#pragma unroll
    for (int r = 0; r < 4; ++r) {
      int m = tm + wm + mi * 16 + quad * 4 + r;
      if (m >= g.M) continue;
#pragma unroll
      for (int ni = 0; ni < 2; ++ni) {
        int n = tn + wn + ni * 16 + lm;
        if (n >= g.N) continue;
        int nl = n - O.n0;
        float v = acc[mi][ni][r] * g.alpha;
        if (O.bias)  v += O.bias[nl];
        if (O.resid) v += O.resid[(long long)m * O.ldcf + nl];
        if (O.Cf)    O.Cf[(long long)m * O.ldcf + nl] = v;
        if (O.Cb) {
          long long idx = O.transV
              ? ((long long)(m >> 10) * 1048576 + (long long)nl * 1024 + (m & 1023))
              : ((long long)m * O.ldcb + nl);
          O.Cb[idx] = (f16)v;
        }
      }
    }
  }
}

// ---------------- pipelined 128x128 8-wave GEMM (2-phase, 2-buffer; measured 58-64us) -------
// Big fused projection only. 64KB LDS -> 2 blocks/CU: cross-block TLP covers the per-step
// drain; within-block the next tile's loads are issued before compute.
__global__ __launch_bounds__(512, 4) void srl_gemm_p(SrlGemmArgs g) {
  __shared__ f16 As[2][8192];
  __shared__ f16 Bs[2][8192];
  const int tid  = threadIdx.x;
  const int wid  = tid >> 6;        // 0..7
  const int lane = tid & 63;

  const int gx  = gridDim.x;
  const int NTt = gx * gridDim.y;
  const int L   = blockIdx.y * gx + blockIdx.x;
  const int W   = ((NTt & 7) == 0) ? ((L & 7) * (NTt >> 3) + (L >> 3)) : L;
  const int tn  = (W % gx) * 128;
  const int tm  = (W / gx) * 128;

  const f16* Ab = g.A + (long long)tm * g.lda;
  const f16* Bb = g.B + (long long)tn * g.ldb;

  // staging maps; LDS layout xor-swizzled: elem (row,k) at row*64 + (((k>>3)+row)&7)*8 + (k&7)
  int aR[2], aO[2];
#pragma unroll
  for (int i = 0; i < 2; ++i) {
    int e = wid * 1024 + i * 512 + lane * 8;
    int r = e >> 6, s = (e >> 3) & 7;
    aR[i] = r; aO[i] = ((s - r) & 7) * 8;
  }

  const int wm = (wid >> 1) * 32;   // 4 wave-rows
  const int wn = (wid & 1) * 64;    // 2 wave-cols
  const int lm = lane & 15;
  const int quad = lane >> 4;

  floatx4 acc[2][4];
#pragma unroll
  for (int a = 0; a < 2; ++a)
#pragma unroll
    for (int b = 0; b < 4; ++b) {
      acc[a][b][0] = 0.f; acc[a][b][1] = 0.f; acc[a][b][2] = 0.f; acc[a][b][3] = 0.f;
    }

  const int nk = g.K >> 6;

  auto stage = [&](int kt, int bsel) {
    const int k0 = kt << 6;
    f16* lA = &As[bsel][0] + wid * 1024;
    f16* lB = &Bs[bsel][0] + wid * 1024;
#pragma unroll
    for (int i = 0; i < 2; ++i)
      GLD_LDS16(Ab + (long long)aR[i] * g.lda + (k0 + aO[i]), lA + i * 512);
#pragma unroll
    for (int i = 0; i < 2; ++i)
      GLD_LDS16(Bb + (long long)aR[i] * g.ldb + (k0 + aO[i]), lB + i * 512);
  };

  stage(0, 0);
  asm volatile("s_waitcnt vmcnt(0)" ::: "memory");
  __builtin_amdgcn_s_barrier();

  auto onestep = [&](int t, int cb) {
    if (t + 1 < nk) stage(t + 1, cb ^ 1);        // issue next-tile loads FIRST
    asm volatile("" ::: "memory");
    const f16* Asb = &As[cb][0];
    const f16* Bsb = &Bs[cb][0];
#pragma unroll
    for (int ks = 0; ks < 2; ++ks) {
      f16x8 af[2], bfr[4];
#pragma unroll
      for (int mi = 0; mi < 2; ++mi) {
        int row = wm + mi * 16 + lm;
        int sg = ((ks * 4 + quad) + row) & 7;
        af[mi] = *(const f16x8*)(Asb + row * 64 + sg * 8);
      }
#pragma unroll
      for (int ni = 0; ni < 4; ++ni) {
        int row = wn + ni * 16 + lm;
        int sg = ((ks * 4 + quad) + row) & 7;
        bfr[ni] = *(const f16x8*)(Bsb + row * 64 + sg * 8);
      }
#pragma unroll
      for (int mi = 0; mi < 2; ++mi)
#pragma unroll
        for (int ni = 0; ni < 4; ++ni)
          acc[mi][ni] = __builtin_amdgcn_mfma_f32_16x16x32_f16(af[mi], bfr[ni], acc[mi][ni], 0, 0, 0);
    }
    asm volatile("s_waitcnt vmcnt(0) lgkmcnt(0)" ::: "memory");
    __builtin_amdgcn_s_barrier();
  };

  for (int t = 0; t < nk; t += 2) {   // nk is even for all routed shapes
    onestep(t, 0);
    onestep(t + 1, 1);
  }

  int oi = 0;
  for (int j = 1; j < g.nOuts; ++j)
    if (tn >= g.out[j].n0) oi = j;
  const SrlOut O = g.out[oi];
#pragma unroll
  for (int mi = 0; mi < 2; ++mi) {
#pragma unroll
    for (int r = 0; r < 4; ++r) {
      int m = tm + wm + mi * 16 + quad * 4 + r;
#pragma unroll
      for (int ni = 0; ni < 4; ++ni) {
        int n = tn + wn + ni * 16 + lm;
        int nl = n - O.n0;
        float v = acc[mi][ni][r] * g.alpha;
        if (O.bias)  v += O.bias[nl];
        if (O.resid) v += O.resid[(long long)m * O.ldcf + nl];
        if (O.Cf)    O.Cf[(long long)m * O.ldcf + nl] = v;
        if (O.Cb) {
          long long idx = O.transV
              ? ((long long)(m >> 10) * 1048576 + (long long)nl * 1024 + (m & 1023))
              : ((long long)m * O.ldcb + nl);
          O.Cb[idx] = (f16)v;
        }
      }
    }
  }
}

// ---------------- fused flash attention: per-block (b,head,qtile=128), S=1024, d=64 ----------
// K/V staging is T14 async-split (global->reg->LDS): loads for tile t+1 are issued at the TOP
// of tile t's compute, and written to LDS between two barriers after compute. (r4-measured win;
// T14 pays here because the compute phase covers the latency.)
struct SrlFlashArgs {
  const f16* Q; const f16* K; const f16* VT; f16* O;
  long long sQb, sKb, sVb;
  float scale;   // includes log2(e)
};

__global__ __launch_bounds__(256, 2) void srl_flash(SrlFlashArgs a) {
  __shared__ f16 Qs[8192];
  __shared__ f16 Ks[8192];
  __shared__ f16 VTs[8192];
  __shared__ f16 Ps[4][4096];
  const int tid = threadIdx.x, wid = tid >> 6, lane = tid & 63;
  const int quad = lane >> 4, c = lane & 15;
  const int L = blockIdx.x;
  const int bh = (L & 7) + ((L >> 6) << 3);
  const int qt = (L >> 3) & 7;
  const int b = bh >> 4, h = bh & 15;
  const f16* Qg = a.Q + (long long)b * a.sQb + (long long)qt * 131072 + h * 64;
  const f16* Kg = a.K + (long long)b * a.sKb + h * 64;
  const f16* Vg = a.VT + (long long)b * a.sVb + (long long)h * 65536;
  f16* Og = a.O + (long long)b * 1048576 + (long long)qt * 131072 + h * 64;

  int rRow[4], rOff[4];
#pragma unroll
  for (int i = 0; i < 4; ++i) {
    int e = wid * 2048 + i * 512 + lane * 8;
    int r = e >> 6, gL = (e >> 3) & 7;
    rRow[i] = r; rOff[i] = ((gL - r) & 7) * 8;
  }
  int vRow[4], vOff[4];
#pragma unroll
  for (int i = 0; i < 4; ++i) {
    int e = wid * 2048 + i * 512 + lane * 8;
    int d = e >> 7, gL = (e >> 3) & 15;
    vRow[i] = d; vOff[i] = ((gL - (d & 7)) & 15) * 8;
  }

  // prologue: Q via global_load_lds; K/V tile 0 via reg-stage; one barrier covers all
#pragma unroll
  for (int i = 0; i < 4; ++i)
    GLD_LDS16(Qg + (long long)rRow[i] * 1024 + rOff[i], Qs + wid * 2048 + i * 512);

  f16x8 kreg[4], vreg[4];
#pragma unroll
  for (int i = 0; i < 4; ++i)
    kreg[i] = *(const f16x8*)(Kg + (long long)rRow[i] * 1024 + rOff[i]);
#pragma unroll
  for (int i = 0; i < 4; ++i)
    vreg[i] = *(const f16x8*)(Vg + (long long)vRow[i] * 1024 + vOff[i]);
#pragma unroll
  for (int i = 0; i < 4; ++i)
    *(f16x8*)(Ks + wid * 2048 + i * 512 + lane * 8) = kreg[i];
#pragma unroll
  for (int i = 0; i < 4; ++i)
    *(f16x8*)(VTs + wid * 2048 + i * 512 + lane * 8) = vreg[i];
  __syncthreads();

  const int wq = wid * 32;
  f16x8 qf[2][2];
#pragma unroll
  for (int nf = 0; nf < 2; ++nf)
#pragma unroll
    for (int ch = 0; ch < 2; ++ch) {
      int row = wq + nf * 16 + c;
      int slot = ((ch * 4 + quad) + row) & 7;
      f16x8 v = *(const f16x8*)(Qs + row * 64 + slot * 8);
      f16 sc = (f16)a.scale;
#pragma unroll
      for (int j = 0; j < 8; ++j) v[j] = v[j] * sc;
      qf[nf][ch] = v;
    }

  float l_s[2] = {0.f, 0.f};
  floatx4 Oa[2][4];
#pragma unroll
  for (int nf = 0; nf < 2; ++nf)
#pragma unroll
    for (int no = 0; no < 4; ++no) {
      Oa[nf][no][0] = 0.f; Oa[nf][no][1] = 0.f; Oa[nf][no][2] = 0.f; Oa[nf][no][3] = 0.f;
    }

  for (int t = 0; t < 8; ++t) {
    // issue next tile's K/V loads into registers FIRST — they land during this tile's compute
    if (t < 7) {
#pragma unroll
      for (int i = 0; i < 4; ++i)
        kreg[i] = *(const f16x8*)(Kg + (long long)((t + 1) * 128 + rRow[i]) * 1024 + rOff[i]);
#pragma unroll
      for (int i = 0; i < 4; ++i)
        vreg[i] = *(const f16x8*)(Vg + (long long)vRow[i] * 1024 + ((t + 1) * 128 + vOff[i]));
    }

    floatx4 sT[2][8];
#pragma unroll
    for (int nf = 0; nf < 2; ++nf)
#pragma unroll
      for (int mf = 0; mf < 8; ++mf) {
        sT[nf][mf][0] = 0.f; sT[nf][mf][1] = 0.f; sT[nf][mf][2] = 0.f; sT[nf][mf][3] = 0.f;
      }
    __builtin_amdgcn_s_setprio(1);
#pragma unroll
    for (int ch = 0; ch < 2; ++ch)
#pragma unroll
      for (int mf = 0; mf < 8; ++mf) {
        int key = mf * 16 + c;
        int slot = ((ch * 4 + quad) + key) & 7;
        f16x8 kf = *(const f16x8*)(Ks + key * 64 + slot * 8);
        sT[0][mf] = __builtin_amdgcn_mfma_f32_16x16x32_f16(kf, qf[0][ch], sT[0][mf], 0, 0, 0);
        sT[1][mf] = __builtin_amdgcn_mfma_f32_16x16x32_f16(kf, qf[1][ch], sT[1][mf], 0, 0, 0);
      }
    __builtin_amdgcn_s_setprio(0);

#pragma unroll
    for (int nf = 0; nf < 2; ++nf) {
      float lt = 0.f;
      const int q = nf * 16 + c;
#pragma unroll
      for (int mf = 0; mf < 8; ++mf) {
        f16x4 pk;
#pragma unroll
        for (int r = 0; r < 4; ++r) {
          float p = __builtin_amdgcn_exp2f(sT[nf][mf][r]);
          lt += p;
          pk[r] = (f16)p;
        }
        int kg = mf * 2 + (quad >> 1), sub = (quad & 1) * 4;
        int slot = (kg + (q & 7)) & 15;
        *(f16x4*)(Ps[wid] + q * 128 + slot * 8 + sub) = pk;
      }
      lt += __shfl_xor(lt, 16);
      lt += __shfl_xor(lt, 32);
      l_s[nf] += lt;
    }
#pragma unroll
    for (int cc = 0; cc < 4; ++cc) {
      f16x8 af[2];
#pragma unroll
      for (int nf = 0; nf < 2; ++nf) {
        int q = nf * 16 + c;
        int slot = ((cc * 4 + quad) + (q & 7)) & 15;
        af[nf] = *(const f16x8*)(Ps[wid] + q * 128 + slot * 8);
      }
      __builtin_amdgcn_s_setprio(1);
#pragma unroll
      for (int no = 0; no < 4; ++no) {
        int d = no * 16 + c;
        int slot = ((cc * 4 + quad) + (d & 7)) & 15;
        f16x8 vf = *(const f16x8*)(VTs + d * 128 + slot * 8);
        Oa[0][no] = __builtin_amdgcn_mfma_f32_16x16x32_f16(af[0], vf, Oa[0][no], 0, 0, 0);
        Oa[1][no] = __builtin_amdgcn_mfma_f32_16x16x32_f16(af[1], vf, Oa[1][no], 0, 0, 0);
      }
      __builtin_amdgcn_s_setprio(0);
    }

    // write the prefetched tile: barrier (all waves done reading t) -> ds_write -> barrier
    if (t < 7) {
      __syncthreads();
#pragma unroll
      for (int i = 0; i < 4; ++i)
        *(f16x8*)(Ks + wid * 2048 + i * 512 + lane * 8) = kreg[i];
#pragma unroll
      for (int i = 0; i < 4; ++i)
        *(f16x8*)(VTs + wid * 2048 + i * 512 + lane * 8) = vreg[i];
      __syncthreads();
    }
  }

#pragma unroll
  for (int nf = 0; nf < 2; ++nf)
#pragma unroll
    for (int r = 0; r < 4; ++r) {
      float li = 1.f / __shfl(l_s[nf], quad * 4 + r);
      int qrow = wq + nf * 16 + quad * 4 + r;
#pragma unroll
      for (int no = 0; no < 4; ++no)
        Qs[qrow * 64 + no * 16 + c] = (f16)(Oa[nf][no][r] * li);
    }
  __syncthreads();
#pragma unroll
  for (int i = 0; i < 4; ++i) {
    int e = wid * 2048 + i * 512 + lane * 8;
    int row = e >> 6, col = e & 63;
    *(f16x8*)(Og + (long long)row * 1024 + col) = *(const f16x8*)(Qs + e);
  }
}

// ---------------- rule softmax: fp32 logits [rows,512] -> f16 probs ----------------
__global__ __launch_bounds__(256) void srl_softmax_rule(const float* logits, f16* probs) {
  __shared__ float red[16];
  const long long row = blockIdx.x;
  const float* p = logits + row * 512;
  const int tid = threadIdx.x;
  float v0 = p[tid], v1 = p[tid + 256];
  float mx = fmaxf(v0, v1);
#pragma unroll
  for (int o = 32; o > 0; o >>= 1) mx = fmaxf(mx, __shfl_down(mx, o));
  const int wid = tid >> 6, lane = tid & 63;
  if (lane == 0) red[wid] = mx;
  __syncthreads();
  if (tid == 0) red[8] = fmaxf(fmaxf(red[0], red[1]), fmaxf(red[2], red[3]));
  __syncthreads();
  mx = red[8];
  float e0 = __expf(v0 - mx), e1 = __expf(v1 - mx);
  float s = e0 + e1;
#pragma unroll
  for (int o = 32; o > 0; o >>= 1) s += __shfl_down(s, o);
  if (lane == 0) red[wid + 4] = s;
  __syncthreads();
  if (tid == 0) red[9] = 1.f / (red[4] + red[5] + red[6] + red[7]);
  __syncthreads();
  const float inv = red[9];
  probs[row * 512 + tid] = (f16)(e0 * inv);
  probs[row * 512 + tid + 256] = (f16)(e1 * inv);
}

// ---------------- LayerNorm + exact GELU: fp32 [rows,1024] -> f16 ----------------
__global__ __launch_bounds__(256) void srl_ln_gelu(const float* x, const float* gam, const float* bet, f16* out) {
  __shared__ float red[16];
  const long long row = blockIdx.x;
  const float* p = x + row * 1024;
  const int tid = threadIdx.x;
  float4 xv = *(const float4*)(p + tid * 4);
  float v[4] = {xv.x, xv.y, xv.z, xv.w};
  float s = v[0] + v[1] + v[2] + v[3];
  float s2 = v[0] * v[0] + v[1] * v[1] + v[2] * v[2] + v[3] * v[3];
#pragma unroll
  for (int o = 32; o > 0; o >>= 1) { s += __shfl_down(s, o); s2 += __shfl_down(s2, o); }
  const int wid = tid >> 6, lane = tid & 63;
  if (lane == 0) { red[wid] = s; red[wid + 4] = s2; }
  __syncthreads();
  if (tid == 0) {
    float ts = red[0] + red[1] + red[2] + red[3];
    float ts2 = red[4] + red[5] + red[6] + red[7];
    float mu = ts * (1.f / 1024.f);
    float var = ts2 * (1.f / 1024.f) - mu * mu;
    red[8] = mu;
    red[9] = rsqrtf(var + 1e-5f);
  }
  __syncthreads();
  const float mu = red[8], rstd = red[9];
  f16x4 o4;
#pragma unroll
  for (int i = 0; i < 4; ++i) {
    int c = tid * 4 + i;
    float t = (v[i] - mu) * rstd * gam[c] + bet[c];
    float ge = 0.5f * t * (1.f + erff(t * 0.70710678118654752f));
    o4[i] = (f16)ge;
  }
  *(f16x4*)(out + row * 1024 + tid * 4) = o4;
}

// ---------------- batched weight convert (+optional transpose) fp32 -> f16 ----------------
struct SrlTcEnt { const float* src; f16* dst; int rows, cols, trans, tileStart; };
struct SrlTcArgs { SrlTcEnt e[16]; };

__global__ __launch_bounds__(256) void srl_convert_weights(SrlTcArgs a) {
  __shared__ float t[32][33];
  const int bt = blockIdx.x;
  int ei = 0;
#pragma unroll
  for (int j = 1; j < 16; ++j)
    if (bt >= a.e[j].tileStart) ei = j;
  SrlTcEnt E = a.e[ei];
  const int lt = bt - E.tileStart;
  const int tcols = E.cols >> 5;
  const int tr = lt / tcols;
  const int tc = lt - tr * tcols;
  const int r = threadIdx.x >> 5;
  const int c = threadIdx.x & 31;
  if (!E.trans) {
#pragma unroll
    for (int p = 0; p < 4; ++p) {
      long long rr = tr * 32 + r + p * 8;
      long long idx = rr * E.cols + tc * 32 + c;
      E.dst[idx] = (f16)E.src[idx];
    }
  } else {
#pragma unroll
    for (int p = 0; p < 4; ++p)
      t[r + p * 8][c] = E.src[(long long)(tr * 32 + r + p * 8) * E.cols + tc * 32 + c];
    __syncthreads();
#pragma unroll
    for (int p = 0; p < 4; ++p)
      E.dst[(long long)(tc * 32 + r + p * 8) * E.rows + tr * 32 + c] = (f16)t[c][r + p * 8];
  }
}

// ---------------- fused bias prep ----------------
__global__ __launch_bounds__(256) void srl_prep_bias(const float* rsel_b, const float* bq,
                                                     const float* bk, const float* bv,
                                                     const float* bmq, const float* maq_w,
                                                     const float* bmaq,
                                                     float* bias_qkvr, float* bcomp) {
  int i = blockIdx.x * 256 + threadIdx.x;
  if (i < 3584) {
    float v;
    if (i < 512) v = rsel_b[i];
    else if (i < 1536) v = bq[i - 512];
    else if (i < 2560) v = bk[i - 1536];
    else v = bv[i - 2560];
    bias_qkvr[i] = v;
  } else if (i < 3584 + 1024) {
    int m = i - 3584;
    float s = bmaq[m];
    for (int t = 0; t < 1024; ++t) s += bmq[t] * maq_w[(long long)t * 1024 + m];
    bcomp[m] = s;
  }
}

// ---------------- h init / finalize ----------------
__global__ __launch_bounds__(256) void srl_h_init(const float* hidden, float* hf, f16* hx) {
  long long base = ((long long)blockIdx.x * 256 + threadIdx.x) * 4;
  float4 v = *(const float4*)(hidden + base);
  *(float4*)(hf + base) = v;
  long long row = base >> 10;
  int col = (int)(base & 1023);
  f16x4 b;
  b[0] = (f16)v.x; b[1] = (f16)v.y; b[2] = (f16)v.z; b[3] = (f16)v.w;
  *(f16x4*)(hx + row * 2048 + col) = b;
}

__global__ __launch_bounds__(256) void srl_finalize(const float* hf, const float* w, const float* b,
                                                    float* out, float* conf) {
  const int bid = blockIdx.x;
  if (bid < 4096) {
    long long base = ((long long)bid * 256 + threadIdx.x) * 4;
    *(float4*)(out + base) = *(const float4*)(hf + base);
  } else {
    const int row = (bid - 4096) * 4 + (threadIdx.x >> 6);
    const int lane = threadIdx.x & 63;
    const float* p = hf + (long long)row * 1024;
    float s = 0.f;
    for (int j = lane; j < 1024; j += 64) s += p[j] * w[j];
#pragma unroll
    for (int o = 32; o > 0; o >>= 1) s += __shfl_down(s, o);
    if (lane == 0) conf[row] = 1.f / (1.f + __expf(-(s + b[0])));
  }
}

// =====================================================================================
extern "C" void kernel_launch(void* const* d_in, const int* in_sizes, int n_in,
                              void* d_out, int out_size, void* d_ws, size_t ws_size,
                              hipStream_t stream) {
  (void)in_sizes; (void)n_in; (void)out_size; (void)ws_size;
  const float* in_hidden   = (const float*)d_in[0];
  const float* in_rule_emb = (const float*)d_in[1];
  const float* in_rsel_w   = (const float*)d_in[2];
  const float* in_rsel_b   = (const float*)d_in[3];
  const float* in_attn_wq  = (const float*)d_in[4];
  const float* in_attn_bq  = (const float*)d_in[5];
  const float* in_attn_wk  = (const float*)d_in[6];
  const float* in_attn_bk  = (const float*)d_in[7];
  const float* in_attn_wv  = (const float*)d_in[8];
  const float* in_attn_bv  = (const float*)d_in[9];
  const float* in_attn_wo  = (const float*)d_in[10];
  const float* in_attn_bo  = (const float*)d_in[11];
  const float* in_memory   = (const float*)d_in[12];
  const float* in_mq_w     = (const float*)d_in[13];
  const float* in_mq_b     = (const float*)d_in[14];
  const float* in_mk_w     = (const float*)d_in[15];
  const float* in_mk_b     = (const float*)d_in[16];
  const float* in_mv_w     = (const float*)d_in[17];
  const float* in_mv_b     = (const float*)d_in[18];
  const float* in_maq_w    = (const float*)d_in[19];
  const float* in_maq_b    = (const float*)d_in[20];
  const float* in_mak_w    = (const float*)d_in[21];
  const float* in_mak_b    = (const float*)d_in[22];
  const float* in_mav_w    = (const float*)d_in[23];
  const float* in_mav_b    = (const float*)d_in[24];
  const float* in_mao_w    = (const float*)d_in[25];
  const float* in_mao_b    = (const float*)d_in[26];
  const float* in_ra_w1    = (const float*)d_in[27];
  const float* in_ra_b1    = (const float*)d_in[28];
  const float* in_ln_s     = (const float*)d_in[29];
  const float* in_ln_b     = (const float*)d_in[30];
  const float* in_ra_w2    = (const float*)d_in[31];
  const float* in_ra_b2    = (const float*)d_in[32];
  const float* in_conf_w   = (const float*)d_in[33];
  const float* in_conf_b   = (const float*)d_in[34];

  char* ws = (char*)d_ws;
  size_t off = 0;
  auto alloc = [&](size_t bytes) -> void* {
    void* p = ws + off;
    off = (off + bytes + 255) & ~(size_t)255;
    return p;
  };
  f16* wt_qkvr    = (f16*)alloc(3584 * 1024 * 2);
  float* bias_qkvr= (float*)alloc(3584 * 4);
  f16* wt_attn_o  = (f16*)alloc(1048576 * 2);
  f16* wt_mq_comp = (f16*)alloc(1048576 * 2);
  float* bcomp    = (float*)alloc(1024 * 4);
  f16* wt_mattn_o = (f16*)alloc(1048576 * 2);
  f16* wt_ra1     = (f16*)alloc(2097152 * 2);
  f16* wt_ra2     = (f16*)alloc(1048576 * 2);
  f16* wt_remb    = (f16*)alloc(524288 * 2);
  f16* wt_mem_kv  = (f16*)alloc(2097152 * 2);
  f16* wt_mattn_k = (f16*)alloc(1048576 * 2);
  f16* wt_mattn_v = (f16*)alloc(1048576 * 2);
  f16* mem_h      = (f16*)alloc(1048576 * 2);
  f16* mk_h       = (f16*)alloc(1048576 * 2);
  f16* mv_h       = (f16*)alloc(1048576 * 2);
  f16* mak_h      = (f16*)alloc(1048576 * 2);
  f16* mavT_h     = (f16*)alloc(1048576 * 2);
  float* h_f      = (float*)alloc(4194304 * 4);
  f16* hx         = (f16*)alloc(8388608 * 2);
  f16* q_h        = (f16*)alloc(4194304 * 2);
  f16* k_h        = (f16*)alloc(4194304 * 2);
  f16* vT_h       = (f16*)alloc(4194304 * 2);
  f16* ctx_h      = (f16*)alloc(4194304 * 2);
  f16* u_h        = (f16*)alloc(4194304 * 2);
  char* arena     = (char*)alloc(16777216);
  float* logits_f = (float*)arena;
  f16* probs_h    = (f16*)(arena + 8388608);
  float* ra1_f    = (float*)arena;
  f16* mqw_nt     = (f16*)arena;
  f16* wmaq_t     = (f16*)(arena + 2097152);

  auto mkOut = [](int n0, const float* bias, const float* resid, float* Cf, int ldcf,
                  f16* Cb, int ldcb, int transV, long long sCb, long long sCh) {
    SrlOut o;
    o.n0 = n0; o.bias = bias; o.resid = resid; o.Cf = Cf; o.Cb = Cb;
    o.ldcf = ldcf; o.ldcb = ldcb; o.transV = transV; o.sCb = sCb; o.sCh = sCh;
    return o;
  };
  // pipelined 128x128 kernel (big fused projection only)
  auto runP = [&](int M, int N, int K, const f16* A, int lda, const f16* B, int ldb,
                  float alpha, SrlGemmArgs g) {
    g.A = A; g.B = B; g.M = M; g.N = N; g.K = K; g.lda = lda; g.ldb = ldb;
    g.sAb = 0; g.sAh = 0; g.sBb = 0; g.sBh = 0; g.alpha = alpha;
    dim3 grid(N / 128, M / 128, 1);
    hipLaunchKernelGGL(srl_gemm_p, grid, dim3(512), 0, stream, g);
  };
  // 64x64 no-LDS kernel: all N<=2048 GEMMs
  auto runS = [&](int M, int N, int K, const f16* A, int lda, const f16* B, int ldb,
                  float alpha, const float* bias, const float* resid, float* Cf, int ldcf,
                  f16* Cb, int ldcb, int transV) {
    SrlGemmArgs g{};
    g.nOuts = 1;
    g.out[0] = mkOut(0, bias, resid, Cf, ldcf, Cb, ldcb, transV, 0, 0);
    g.A = A; g.B = B; g.M = M; g.N = N; g.K = K; g.lda = lda; g.ldb = ldb;
    g.sAb = 0; g.sAh = 0; g.sBb = 0; g.sBh = 0; g.alpha = alpha;
    dim3 grid((N + 63) / 64, (M + 63) / 64, 1);
    hipLaunchKernelGGL((srl_gemm<4>), grid, dim3(256), 0, stream, g);
  };
  auto runSm = [&](int M, int N, int K, const f16* A, int lda, const f16* B, int ldb,
                   float alpha, SrlGemmArgs g) {
    g.A = A; g.B = B; g.M = M; g.N = N; g.K = K; g.lda = lda; g.ldb = ldb;
    g.sAb = 0; g.sAh = 0; g.sBb = 0; g.sBh = 0; g.alpha = alpha;
    dim3 grid((N + 63) / 64, (M + 63) / 64, 1);
    hipLaunchKernelGGL((srl_gemm<4>), grid, dim3(256), 0, stream, g);
  };

  // ---- one-time weight convert/transpose ----
  SrlTcArgs tc;
  int ts = 0;
  auto setent = [&](int i, const float* s, f16* d, int rows, int cols, int trans) {
    tc.e[i].src = s; tc.e[i].dst = d; tc.e[i].rows = rows; tc.e[i].cols = cols;
    tc.e[i].trans = trans; tc.e[i].tileStart = ts;
    ts += (rows / 32) * (cols / 32);
  };
  setent(0,  in_attn_wq, wt_qkvr + 512 * 1024, 1024, 1024, 1);
  setent(1,  in_attn_wk, wt_qkvr + 1536 * 1024, 1024, 1024, 1);
  setent(2,  in_attn_wv, wt_qkvr + 2560 * 1024, 1024, 1024, 1);
  setent(3,  in_rsel_w,  wt_qkvr, 1024, 512, 1);
  setent(4,  in_attn_wo, wt_attn_o, 1024, 1024, 1);
  setent(5,  in_mq_w,    mqw_nt, 1024, 1024, 0);
  setent(6,  in_maq_w,   wmaq_t, 1024, 1024, 1);
  setent(7,  in_mak_w,   wt_mattn_k, 1024, 1024, 1);
  setent(8,  in_mav_w,   wt_mattn_v, 1024, 1024, 1);
  setent(9,  in_mk_w,    wt_mem_kv, 1024, 1024, 1);
  setent(10, in_mv_w,    wt_mem_kv + 1048576, 1024, 1024, 1);
  setent(11, in_mao_w,   wt_mattn_o, 1024, 1024, 1);
  setent(12, in_ra_w1,   wt_ra1, 2048, 1024, 1);
  setent(13, in_ra_w2,   wt_ra2, 1024, 1024, 1);
  setent(14, in_rule_emb, wt_remb, 512, 1024, 1);
  setent(15, in_memory,  mem_h, 1024, 1024, 0);
  hipLaunchKernelGGL(srl_convert_weights, dim3(ts), dim3(256), 0, stream, tc);
  hipLaunchKernelGGL(srl_prep_bias, dim3(18), dim3(256), 0, stream,
                     in_rsel_b, in_attn_bq, in_attn_bk, in_attn_bv,
                     in_mq_b, in_maq_w, in_maq_b, bias_qkvr, bcomp);
  hipLaunchKernelGGL(srl_h_init, dim3(4096), dim3(256), 0, stream, in_hidden, h_f, hx);

  // ---- preamble GEMMs (M=1024, run once) ----
  {
    SrlGemmArgs g{};
    g.nOuts = 2;
    g.out[0] = mkOut(0, in_mk_b, nullptr, nullptr, 0, mk_h, 1024, 0, 0, 0);
    g.out[1] = mkOut(1024, in_mv_b, nullptr, nullptr, 0, mv_h, 1024, 0, 0, 0);
    runSm(1024, 2048, 1024, mem_h, 1024, wt_mem_kv, 1024, 1.f, g);
  }
  runS(1024, 1024, 1024, mk_h, 1024, wt_mattn_k, 1024, 1.f, in_mak_b, nullptr, nullptr, 0, mak_h, 1024, 0);
  runS(1024, 1024, 1024, mv_h, 1024, wt_mattn_v, 1024, 1.f, in_mav_b, nullptr, nullptr, 0, mavT_h, 0, 1);
  runS(1024, 1024, 1024, wmaq_t, 1024, mqw_nt, 1024, 1.f, nullptr, nullptr, nullptr, 0, wt_mq_comp, 1024, 0);

  const float kLog2e = 1.4426950408889634f;
  for (int step = 0; step < 3; ++step) {
    {  // fused rule-logits + Q + K + V projection: 128x128 pipelined, 896 blocks
      SrlGemmArgs g{};
      g.nOuts = 4;
      g.out[0] = mkOut(0,    bias_qkvr,        nullptr, logits_f, 512, nullptr, 0, 0, 0, 0);
      g.out[1] = mkOut(512,  bias_qkvr + 512,  nullptr, nullptr, 0, q_h, 1024, 0, 0, 0);
      g.out[2] = mkOut(1536, bias_qkvr + 1536, nullptr, nullptr, 0, k_h, 1024, 0, 0, 0);
      g.out[3] = mkOut(2560, bias_qkvr + 2560, nullptr, nullptr, 0, vT_h, 0, 1, 0, 0);
      runP(4096, 3584, 1024, hx, 2048, wt_qkvr, 1024, 1.f, g);
    }
    hipLaunchKernelGGL(srl_softmax_rule, dim3(4096), dim3(256), 0, stream, logits_f, probs_h);
    runS(4096, 1024, 512, probs_h, 512, wt_remb, 512, 1.f, nullptr, nullptr, nullptr, 0, hx + 1024, 2048, 0);
    {
      SrlFlashArgs fa;
      fa.Q = q_h; fa.K = k_h; fa.VT = vT_h; fa.O = ctx_h;
      fa.sQb = 1048576; fa.sKb = 1048576; fa.sVb = 1048576; fa.scale = 0.125f * kLog2e;
      hipLaunchKernelGGL(srl_flash, dim3(512), dim3(256), 0, stream, fa);
    }
    runS(4096, 1024, 1024, ctx_h, 1024, wt_attn_o, 1024, 1.f, in_attn_bo, h_f, h_f, 1024, hx, 2048, 0);
    runS(4096, 1024, 1024, hx, 2048, wt_mq_comp, 1024, 1.f, bcomp, nullptr, nullptr, 0, k_h, 1024, 0);
    {
      SrlFlashArgs fa;
      fa.Q = k_h; fa.K = mak_h; fa.VT = mavT_h; fa.O = ctx_h;
      fa.sQb = 1048576; fa.sKb = 0; fa.sVb = 0; fa.scale = 0.125f * kLog2e;
      hipLaunchKernelGGL(srl_flash, dim3(512), dim3(256), 0, stream, fa);
    }
    runS(4096, 1024, 1024, ctx_h, 1024, wt_mattn_o, 1024, 1.f, in_mao_b, h_f, h_f, 1024, hx, 2048, 0);
    runS(4096, 1024, 2048, hx, 2048, wt_ra1, 2048, 1.f, in_ra_b1, nullptr, ra1_f, 1024, nullptr, 0, 0);
    hipLaunchKernelGGL(srl_ln_gelu, dim3(4096), dim3(256), 0, stream, ra1_f, in_ln_s, in_ln_b, u_h);
    runS(4096, 1024, 1024, u_h, 1024, wt_ra2, 1024, 1.f, in_ra_b2, h_f, h_f, 1024, hx, 2048, 0);
  }

  hipLaunchKernelGGL(srl_finalize, dim3(5120), dim3(256), 0, stream, h_f, in_conf_w, in_conf_b,
                     (float*)d_out, (float*)d_out + 4194304);
}

// Round 9
// 1110.399 us; speedup vs baseline: 1.7366x; 1.7366x over previous
//
#include <hip/hip_runtime.h>
#include <stdint.h>

typedef _Float16 f16;
typedef __attribute__((ext_vector_type(4))) float floatx4;
typedef __attribute__((ext_vector_type(8))) f16   f16x8;
typedef __attribute__((ext_vector_type(4))) f16   f16x4;

#define GLD_LDS16(gp, lp)                                                                      \
  __builtin_amdgcn_global_load_lds((const __attribute__((address_space(1))) void*)(uintptr_t)(gp), \
                                   (__attribute__((address_space(3))) void*)(uintptr_t)(lp), 16, 0, 0)

// ---------------- generalized f16 MFMA GEMM: C = alpha*A@B^T (+bias)(+resid) ----------------
struct SrlOut {
  int n0;
  const float* bias;
  const float* resid;
  float* Cf; f16* Cb;
  int ldcf, ldcb, transV;
  long long sCb, sCh;
};
struct SrlGemmArgs {
  const f16* A; const f16* B;
  int M, N, K, lda, ldb;
  long long sAb, sAh, sBb, sBh;
  float alpha;
  int nOuts;
  SrlOut out[4];
};

// 64x64 single-buffer DMA-staged kernel: 1024 blocks -> 4 blocks/CU, 16 waves/CU.
// MEASURED OPTIMUM for the latency-bound 4096x1024 in-loop GEMMs across the full ablation
// matrix (r0..r8): beats 128x128 pipelined @1 block/CU (r1), 128x64 @8 waves/CU (r3),
// T14 reg-stage (r5: compute phase < load latency), BK=128 (r6: fatter drains),
// 2-phase double-buffer (r7), and no-LDS direct fragments (r8: uncoalesced, 2KB lane
// stride -> 52MB FETCH). The naive structure + max block TLP wins at this shape.
template<int BM, int BN, int MINW>
__global__ __launch_bounds__(256, MINW) void srl_gemm(SrlGemmArgs g) {
  constexpr int BK = 64;
  constexpr int ACH = BM / 32;
  constexpr int BCH = BN / 32;
  constexpr int MI  = 2;
  constexpr int NI  = 2;
  __shared__ f16 As[BM * BK];
  __shared__ f16 Bs[BN * BK];
  const int tid  = threadIdx.x;
  const int wid  = tid >> 6;
  const int lane = tid & 63;

  const int gx = gridDim.x;
  const int NT = gx * gridDim.y;
  const int L  = blockIdx.y * gx + blockIdx.x;
  const int W  = ((NT & 7) == 0) ? ((L & 7) * (NT >> 3) + (L >> 3)) : L;
  const int tn = (W % gx) * BN;
  const int tm = (W / gx) * BM;

  const f16* Ab = g.A + (long long)tm * g.lda;
  const f16* Bb = g.B + (long long)tn * g.ldb;
  const int maxAr = g.M - 1 - tm;
  const int maxBr = g.N - 1 - tn;

  // staging maps; LDS layout xor-swizzled: elem (row,k) at row*64 + (((k>>3)+row)&7)*8 + (k&7)
  int aR[ACH], aO[ACH];
#pragma unroll
  for (int i = 0; i < ACH; ++i) {
    int e = wid * (BM * 16) + i * 512 + lane * 8;
    int r = e >> 6, s = (e >> 3) & 7;
    aR[i] = (r <= maxAr) ? r : maxAr;
    aO[i] = ((s - r) & 7) * 8;
  }
  int bR[BCH], bO[BCH];
#pragma unroll
  for (int i = 0; i < BCH; ++i) {
    int e = wid * (BN * 16) + i * 512 + lane * 8;
    int r = e >> 6, s = (e >> 3) & 7;
    bR[i] = (r <= maxBr) ? r : maxBr;
    bO[i] = ((s - r) & 7) * 8;
  }
  f16* lA = As + wid * (BM * 16);
  f16* lB = Bs + wid * (BN * 16);

  floatx4 acc[MI][NI];
#pragma unroll
  for (int a = 0; a < MI; ++a)
#pragma unroll
    for (int b = 0; b < NI; ++b) {
      acc[a][b][0] = 0.f; acc[a][b][1] = 0.f; acc[a][b][2] = 0.f; acc[a][b][3] = 0.f;
    }

  const int wm = (wid & 1) * 32;
  const int wn = (wid >> 1) * 32;
  const int lm = lane & 15;
  const int quad = lane >> 4;

  for (int k0 = 0; k0 < g.K; k0 += BK) {
    __syncthreads();
#pragma unroll
    for (int i = 0; i < ACH; ++i)
      GLD_LDS16(Ab + (long long)aR[i] * g.lda + (k0 + aO[i]), lA + i * 512);
#pragma unroll
    for (int i = 0; i < BCH; ++i)
      GLD_LDS16(Bb + (long long)bR[i] * g.ldb + (k0 + bO[i]), lB + i * 512);
    __syncthreads();
#pragma unroll
    for (int ks = 0; ks < 2; ++ks) {
      f16x8 af[MI], bfr[NI];
#pragma unroll
      for (int mi = 0; mi < MI; ++mi) {
        int row = wm + mi * 16 + lm;
        int sg = ((ks * 4 + quad) + row) & 7;
        af[mi] = *(const f16x8*)(As + row * 64 + sg * 8);
      }
#pragma unroll
      for (int ni = 0; ni < NI; ++ni) {
        int row = wn + ni * 16 + lm;
        int sg = ((ks * 4 + quad) + row) & 7;
        bfr[ni] = *(const f16x8*)(Bs + row * 64 + sg * 8);
      }
#pragma unroll
      for (int mi = 0; mi < MI; ++mi)
#pragma unroll
        for (int ni = 0; ni < NI; ++ni)
          acc[mi][ni] = __builtin_amdgcn_mfma_f32_16x16x32_f16(af[mi], bfr[ni], acc[mi][ni], 0, 0, 0);
    }
  }

  int oi = 0;
  for (int j = 1; j < g.nOuts; ++j)
    if (tn >= g.out[j].n0) oi = j;
  const SrlOut O = g.out[oi];
#pragma unroll
  for (int mi = 0; mi < MI; ++mi) {
#pragma unroll
    for (int r = 0; r < 4; ++r) {
      int m = tm + wm + mi * 16 + quad * 4 + r;
      if (m >= g.M) continue;
#pragma unroll
      for (int ni = 0; ni < NI; ++ni) {
        int n = tn + wn + ni * 16 + lm;
        if (n >= g.N) continue;
        int nl = n - O.n0;
        float v = acc[mi][ni][r] * g.alpha;
        if (O.bias)  v += O.bias[nl];
        if (O.resid) v += O.resid[(long long)m * O.ldcf + nl];
        if (O.Cf)    O.Cf[(long long)m * O.ldcf + nl] = v;
        if (O.Cb) {
          long long idx = O.transV
              ? ((long long)(m >> 10) * 1048576 + (long long)nl * 1024 + (m & 1023))
              : ((long long)m * O.ldcb + nl);
          O.Cb[idx] = (f16)v;
        }
      }
    }
  }
}

// ---------------- pipelined 128x128 8-wave GEMM (2-phase, 2-buffer; measured 58-60us) -------
// Big fused projection only. 64KB LDS -> 2 blocks/CU: cross-block TLP covers the per-step
// drain; within-block the next tile's loads are issued before compute.
__global__ __launch_bounds__(512, 4) void srl_gemm_p(SrlGemmArgs g) {
  __shared__ f16 As[2][8192];
  __shared__ f16 Bs[2][8192];
  const int tid  = threadIdx.x;
  const int wid  = tid >> 6;        // 0..7
  const int lane = tid & 63;

  const int gx  = gridDim.x;
  const int NTt = gx * gridDim.y;
  const int L   = blockIdx.y * gx + blockIdx.x;
  const int W   = ((NTt & 7) == 0) ? ((L & 7) * (NTt >> 3) + (L >> 3)) : L;
  const int tn  = (W % gx) * 128;
  const int tm  = (W / gx) * 128;

  const f16* Ab = g.A + (long long)tm * g.lda;
  const f16* Bb = g.B + (long long)tn * g.ldb;

  // staging maps; LDS layout xor-swizzled: elem (row,k) at row*64 + (((k>>3)+row)&7)*8 + (k&7)
  int aR[2], aO[2];
#pragma unroll
  for (int i = 0; i < 2; ++i) {
    int e = wid * 1024 + i * 512 + lane * 8;
    int r = e >> 6, s = (e >> 3) & 7;
    aR[i] = r; aO[i] = ((s - r) & 7) * 8;
  }

  const int wm = (wid >> 1) * 32;   // 4 wave-rows
  const int wn = (wid & 1) * 64;    // 2 wave-cols
  const int lm = lane & 15;
  const int quad = lane >> 4;

  floatx4 acc[2][4];
#pragma unroll
  for (int a = 0; a < 2; ++a)
#pragma unroll
    for (int b = 0; b < 4; ++b) {
      acc[a][b][0] = 0.f; acc[a][b][1] = 0.f; acc[a][b][2] = 0.f; acc[a][b][3] = 0.f;
    }

  const int nk = g.K >> 6;

  auto stage = [&](int kt, int bsel) {
    const int k0 = kt << 6;
    f16* lA = &As[bsel][0] + wid * 1024;
    f16* lB = &Bs[bsel][0] + wid * 1024;
#pragma unroll
    for (int i = 0; i < 2; ++i)
      GLD_LDS16(Ab + (long long)aR[i] * g.lda + (k0 + aO[i]), lA + i * 512);
#pragma unroll
    for (int i = 0; i < 2; ++i)
      GLD_LDS16(Bb + (long long)aR[i] * g.ldb + (k0 + aO[i]), lB + i * 512);
  };

  stage(0, 0);
  asm volatile("s_waitcnt vmcnt(0)" ::: "memory");
  __builtin_amdgcn_s_barrier();

  auto onestep = [&](int t, int cb) {
    if (t + 1 < nk) stage(t + 1, cb ^ 1);        // issue next-tile loads FIRST
    asm volatile("" ::: "memory");
    const f16* Asb = &As[cb][0];
    const f16* Bsb = &Bs[cb][0];
#pragma unroll
    for (int ks = 0; ks < 2; ++ks) {
      f16x8 af[2], bfr[4];
#pragma unroll
      for (int mi = 0; mi < 2; ++mi) {
        int row = wm + mi * 16 + lm;
        int sg = ((ks * 4 + quad) + row) & 7;
        af[mi] = *(const f16x8*)(Asb + row * 64 + sg * 8);
      }
#pragma unroll
      for (int ni = 0; ni < 4; ++ni) {
        int row = wn + ni * 16 + lm;
        int sg = ((ks * 4 + quad) + row) & 7;
        bfr[ni] = *(const f16x8*)(Bsb + row * 64 + sg * 8);
      }
#pragma unroll
      for (int mi = 0; mi < 2; ++mi)
#pragma unroll
        for (int ni = 0; ni < 4; ++ni)
          acc[mi][ni] = __builtin_amdgcn_mfma_f32_16x16x32_f16(af[mi], bfr[ni], acc[mi][ni], 0, 0, 0);
    }
    asm volatile("s_waitcnt vmcnt(0) lgkmcnt(0)" ::: "memory");
    __builtin_amdgcn_s_barrier();
  };

  for (int t = 0; t < nk; t += 2) {   // nk is even for all routed shapes
    onestep(t, 0);
    onestep(t + 1, 1);
  }

  int oi = 0;
  for (int j = 1; j < g.nOuts; ++j)
    if (tn >= g.out[j].n0) oi = j;
  const SrlOut O = g.out[oi];
#pragma unroll
  for (int mi = 0; mi < 2; ++mi) {
#pragma unroll
    for (int r = 0; r < 4; ++r) {
      int m = tm + wm + mi * 16 + quad * 4 + r;
#pragma unroll
      for (int ni = 0; ni < 4; ++ni) {
        int n = tn + wn + ni * 16 + lm;
        int nl = n - O.n0;
        float v = acc[mi][ni][r] * g.alpha;
        if (O.bias)  v += O.bias[nl];
        if (O.resid) v += O.resid[(long long)m * O.ldcf + nl];
        if (O.Cf)    O.Cf[(long long)m * O.ldcf + nl] = v;
        if (O.Cb) {
          long long idx = O.transV
              ? ((long long)(m >> 10) * 1048576 + (long long)nl * 1024 + (m & 1023))
              : ((long long)m * O.ldcb + nl);
          O.Cb[idx] = (f16)v;
        }
      }
    }
  }
}

// ---------------- fused flash attention: per-block (b,head,qtile=128), S=1024, d=64 ----------
// K/V staging is T14 async-split (global->reg->LDS): loads for tile t+1 are issued at the TOP
// of tile t's compute, and written to LDS between two barriers after compute. (r4-measured win;
// T14 pays here because the compute phase covers the latency.)
struct SrlFlashArgs {
  const f16* Q; const f16* K; const f16* VT; f16* O;
  long long sQb, sKb, sVb;
  float scale;   // includes log2(e)
};

__global__ __launch_bounds__(256, 2) void srl_flash(SrlFlashArgs a) {
  __shared__ f16 Qs[8192];
  __shared__ f16 Ks[8192];
  __shared__ f16 VTs[8192];
  __shared__ f16 Ps[4][4096];
  const int tid = threadIdx.x, wid = tid >> 6, lane = tid & 63;
  const int quad = lane >> 4, c = lane & 15;
  const int L = blockIdx.x;
  const int bh = (L & 7) + ((L >> 6) << 3);
  const int qt = (L >> 3) & 7;
  const int b = bh >> 4, h = bh & 15;
  const f16* Qg = a.Q + (long long)b * a.sQb + (long long)qt * 131072 + h * 64;
  const f16* Kg = a.K + (long long)b * a.sKb + h * 64;
  const f16* Vg = a.VT + (long long)b * a.sVb + (long long)h * 65536;
  f16* Og = a.O + (long long)b * 1048576 + (long long)qt * 131072 + h * 64;

  int rRow[4], rOff[4];
#pragma unroll
  for (int i = 0; i < 4; ++i) {
    int e = wid * 2048 + i * 512 + lane * 8;
    int r = e >> 6, gL = (e >> 3) & 7;
    rRow[i] = r; rOff[i] = ((gL - r) & 7) * 8;
  }
  int vRow[4], vOff[4];
#pragma unroll
  for (int i = 0; i < 4; ++i) {
    int e = wid * 2048 + i * 512 + lane * 8;
    int d = e >> 7, gL = (e >> 3) & 15;
    vRow[i] = d; vOff[i] = ((gL - (d & 7)) & 15) * 8;
  }

  // prologue: Q via global_load_lds; K/V tile 0 via reg-stage; one barrier covers all
#pragma unroll
  for (int i = 0; i < 4; ++i)
    GLD_LDS16(Qg + (long long)rRow[i] * 1024 + rOff[i], Qs + wid * 2048 + i * 512);

  f16x8 kreg[4], vreg[4];
#pragma unroll
  for (int i = 0; i < 4; ++i)
    kreg[i] = *(const f16x8*)(Kg + (long long)rRow[i] * 1024 + rOff[i]);
#pragma unroll
  for (int i = 0; i < 4; ++i)
    vreg[i] = *(const f16x8*)(Vg + (long long)vRow[i] * 1024 + vOff[i]);
#pragma unroll
  for (int i = 0; i < 4; ++i)
    *(f16x8*)(Ks + wid * 2048 + i * 512 + lane * 8) = kreg[i];
#pragma unroll
  for (int i = 0; i < 4; ++i)
    *(f16x8*)(VTs + wid * 2048 + i * 512 + lane * 8) = vreg[i];
  __syncthreads();

  const int wq = wid * 32;
  f16x8 qf[2][2];
#pragma unroll
  for (int nf = 0; nf < 2; ++nf)
#pragma unroll
    for (int ch = 0; ch < 2; ++ch) {
      int row = wq + nf * 16 + c;
      int slot = ((ch * 4 + quad) + row) & 7;
      f16x8 v = *(const f16x8*)(Qs + row * 64 + slot * 8);
      f16 sc = (f16)a.scale;
#pragma unroll
      for (int j = 0; j < 8; ++j) v[j] = v[j] * sc;
      qf[nf][ch] = v;
    }

  float l_s[2] = {0.f, 0.f};
  floatx4 Oa[2][4];
#pragma unroll
  for (int nf = 0; nf < 2; ++nf)
#pragma unroll
    for (int no = 0; no < 4; ++no) {
      Oa[nf][no][0] = 0.f; Oa[nf][no][1] = 0.f; Oa[nf][no][2] = 0.f; Oa[nf][no][3] = 0.f;
    }

  for (int t = 0; t < 8; ++t) {
    // issue next tile's K/V loads into registers FIRST — they land during this tile's compute
    if (t < 7) {
#pragma unroll
      for (int i = 0; i < 4; ++i)
        kreg[i] = *(const f16x8*)(Kg + (long long)((t + 1) * 128 + rRow[i]) * 1024 + rOff[i]);
#pragma unroll
      for (int i = 0; i < 4; ++i)
        vreg[i] = *(const f16x8*)(Vg + (long long)vRow[i] * 1024 + ((t + 1) * 128 + vOff[i]));
    }

    floatx4 sT[2][8];
#pragma unroll
    for (int nf = 0; nf < 2; ++nf)
#pragma unroll
      for (int mf = 0; mf < 8; ++mf) {
        sT[nf][mf][0] = 0.f; sT[nf][mf][1] = 0.f; sT[nf][mf][2] = 0.f; sT[nf][mf][3] = 0.f;
      }
    __builtin_amdgcn_s_setprio(1);
#pragma unroll
    for (int ch = 0; ch < 2; ++ch)
#pragma unroll
      for (int mf = 0; mf < 8; ++mf) {
        int key = mf * 16 + c;
        int slot = ((ch * 4 + quad) + key) & 7;
        f16x8 kf = *(const f16x8*)(Ks + key * 64 + slot * 8);
        sT[0][mf] = __builtin_amdgcn_mfma_f32_16x16x32_f16(kf, qf[0][ch], sT[0][mf], 0, 0, 0);
        sT[1][mf] = __builtin_amdgcn_mfma_f32_16x16x32_f16(kf, qf[1][ch], sT[1][mf], 0, 0, 0);
      }
    __builtin_amdgcn_s_setprio(0);

#pragma unroll
    for (int nf = 0; nf < 2; ++nf) {
      float lt = 0.f;
      const int q = nf * 16 + c;
#pragma unroll
      for (int mf = 0; mf < 8; ++mf) {
        f16x4 pk;
#pragma unroll
        for (int r = 0; r < 4; ++r) {
          float p = __builtin_amdgcn_exp2f(sT[nf][mf][r]);
          lt += p;
          pk[r] = (f16)p;
        }
        int kg = mf * 2 + (quad >> 1), sub = (quad & 1) * 4;
        int slot = (kg + (q & 7)) & 15;
        *(f16x4*)(Ps[wid] + q * 128 + slot * 8 + sub) = pk;
      }
      lt += __shfl_xor(lt, 16);
      lt += __shfl_xor(lt, 32);
      l_s[nf] += lt;
    }
#pragma unroll
    for (int cc = 0; cc < 4; ++cc) {
      f16x8 af[2];
#pragma unroll
      for (int nf = 0; nf < 2; ++nf) {
        int q = nf * 16 + c;
        int slot = ((cc * 4 + quad) + (q & 7)) & 15;
        af[nf] = *(const f16x8*)(Ps[wid] + q * 128 + slot * 8);
      }
      __builtin_amdgcn_s_setprio(1);
#pragma unroll
      for (int no = 0; no < 4; ++no) {
        int d = no * 16 + c;
        int slot = ((cc * 4 + quad) + (d & 7)) & 15;
        f16x8 vf = *(const f16x8*)(VTs + d * 128 + slot * 8);
        Oa[0][no] = __builtin_amdgcn_mfma_f32_16x16x32_f16(af[0], vf, Oa[0][no], 0, 0, 0);
        Oa[1][no] = __builtin_amdgcn_mfma_f32_16x16x32_f16(af[1], vf, Oa[1][no], 0, 0, 0);
      }
      __builtin_amdgcn_s_setprio(0);
    }

    // write the prefetched tile: barrier (all waves done reading t) -> ds_write -> barrier
    if (t < 7) {
      __syncthreads();
#pragma unroll
      for (int i = 0; i < 4; ++i)
        *(f16x8*)(Ks + wid * 2048 + i * 512 + lane * 8) = kreg[i];
#pragma unroll
      for (int i = 0; i < 4; ++i)
        *(f16x8*)(VTs + wid * 2048 + i * 512 + lane * 8) = vreg[i];
      __syncthreads();
    }
  }

#pragma unroll
  for (int nf = 0; nf < 2; ++nf)
#pragma unroll
    for (int r = 0; r < 4; ++r) {
      float li = 1.f / __shfl(l_s[nf], quad * 4 + r);
      int qrow = wq + nf * 16 + quad * 4 + r;
#pragma unroll
      for (int no = 0; no < 4; ++no)
        Qs[qrow * 64 + no * 16 + c] = (f16)(Oa[nf][no][r] * li);
    }
  __syncthreads();
#pragma unroll
  for (int i = 0; i < 4; ++i) {
    int e = wid * 2048 + i * 512 + lane * 8;
    int row = e >> 6, col = e & 63;
    *(f16x8*)(Og + (long long)row * 1024 + col) = *(const f16x8*)(Qs + e);
  }
}

// ---------------- rule softmax: fp32 logits [rows,512] -> f16 probs ----------------
__global__ __launch_bounds__(256) void srl_softmax_rule(const float* logits, f16* probs) {
  __shared__ float red[16];
  const long long row = blockIdx.x;
  const float* p = logits + row * 512;
  const int tid = threadIdx.x;
  float v0 = p[tid], v1 = p[tid + 256];
  float mx = fmaxf(v0, v1);
#pragma unroll
  for (int o = 32; o > 0; o >>= 1) mx = fmaxf(mx, __shfl_down(mx, o));
  const int wid = tid >> 6, lane = tid & 63;
  if (lane == 0) red[wid] = mx;
  __syncthreads();
  if (tid == 0) red[8] = fmaxf(fmaxf(red[0], red[1]), fmaxf(red[2], red[3]));
  __syncthreads();
  mx = red[8];
  float e0 = __expf(v0 - mx), e1 = __expf(v1 - mx);
  float s = e0 + e1;
#pragma unroll
  for (int o = 32; o > 0; o >>= 1) s += __shfl_down(s, o);
  if (lane == 0) red[wid + 4] = s;
  __syncthreads();
  if (tid == 0) red[9] = 1.f / (red[4] + red[5] + red[6] + red[7]);
  __syncthreads();
  const float inv = red[9];
  probs[row * 512 + tid] = (f16)(e0 * inv);
  probs[row * 512 + tid + 256] = (f16)(e1 * inv);
}

// ---------------- LayerNorm + exact GELU: fp32 [rows,1024] -> f16 ----------------
__global__ __launch_bounds__(256) void srl_ln_gelu(const float* x, const float* gam, const float* bet, f16* out) {
  __shared__ float red[16];
  const long long row = blockIdx.x;
  const float* p = x + row * 1024;
  const int tid = threadIdx.x;
  float4 xv = *(const float4*)(p + tid * 4);
  float v[4] = {xv.x, xv.y, xv.z, xv.w};
  float s = v[0] + v[1] + v[2] + v[3];
  float s2 = v[0] * v[0] + v[1] * v[1] + v[2] * v[2] + v[3] * v[3];
#pragma unroll
  for (int o = 32; o > 0; o >>= 1) { s += __shfl_down(s, o); s2 += __shfl_down(s2, o); }
  const int wid = tid >> 6, lane = tid & 63;
  if (lane == 0) { red[wid] = s; red[wid + 4] = s2; }
  __syncthreads();
  if (tid == 0) {
    float ts = red[0] + red[1] + red[2] + red[3];
    float ts2 = red[4] + red[5] + red[6] + red[7];
    float mu = ts * (1.f / 1024.f);
    float var = ts2 * (1.f / 1024.f) - mu * mu;
    red[8] = mu;
    red[9] = rsqrtf(var + 1e-5f);
  }
  __syncthreads();
  const float mu = red[8], rstd = red[9];
  f16x4 o4;
#pragma unroll
  for (int i = 0; i < 4; ++i) {
    int c = tid * 4 + i;
    float t = (v[i] - mu) * rstd * gam[c] + bet[c];
    float ge = 0.5f * t * (1.f + erff(t * 0.70710678118654752f));
    o4[i] = (f16)ge;
  }
  *(f16x4*)(out + row * 1024 + tid * 4) = o4;
}

// ---------------- batched weight convert (+optional transpose) fp32 -> f16 ----------------
struct SrlTcEnt { const float* src; f16* dst; int rows, cols, trans, tileStart; };
struct SrlTcArgs { SrlTcEnt e[16]; };

__global__ __launch_bounds__(256) void srl_convert_weights(SrlTcArgs a) {
  __shared__ float t[32][33];
  const int bt = blockIdx.x;
  int ei = 0;
#pragma unroll
  for (int j = 1; j < 16; ++j)
    if (bt >= a.e[j].tileStart) ei = j;
  SrlTcEnt E = a.e[ei];
  const int lt = bt - E.tileStart;
  const int tcols = E.cols >> 5;
  const int tr = lt / tcols;
  const int tc = lt - tr * tcols;
  const int r = threadIdx.x >> 5;
  const int c = threadIdx.x & 31;
  if (!E.trans) {
#pragma unroll
    for (int p = 0; p < 4; ++p) {
      long long rr = tr * 32 + r + p * 8;
      long long idx = rr * E.cols + tc * 32 + c;
      E.dst[idx] = (f16)E.src[idx];
    }
  } else {
#pragma unroll
    for (int p = 0; p < 4; ++p)
      t[r + p * 8][c] = E.src[(long long)(tr * 32 + r + p * 8) * E.cols + tc * 32 + c];
    __syncthreads();
#pragma unroll
    for (int p = 0; p < 4; ++p)
      E.dst[(long long)(tc * 32 + r + p * 8) * E.rows + tr * 32 + c] = (f16)t[c][r + p * 8];
  }
}

// ---------------- fused bias prep ----------------
__global__ __launch_bounds__(256) void srl_prep_bias(const float* rsel_b, const float* bq,
                                                     const float* bk, const float* bv,
                                                     const float* bmq, const float* maq_w,
                                                     const float* bmaq,
                                                     float* bias_qkvr, float* bcomp) {
  int i = blockIdx.x * 256 + threadIdx.x;
  if (i < 3584) {
    float v;
    if (i < 512) v = rsel_b[i];
    else if (i < 1536) v = bq[i - 512];
    else if (i < 2560) v = bk[i - 1536];
    else v = bv[i - 2560];
    bias_qkvr[i] = v;
  } else if (i < 3584 + 1024) {
    int m = i - 3584;
    float s = bmaq[m];
    for (int t = 0; t < 1024; ++t) s += bmq[t] * maq_w[(long long)t * 1024 + m];
    bcomp[m] = s;
  }
}

// ---------------- h init / finalize ----------------
__global__ __launch_bounds__(256) void srl_h_init(const float* hidden, float* hf, f16* hx) {
  long long base = ((long long)blockIdx.x * 256 + threadIdx.x) * 4;
  float4 v = *(const float4*)(hidden + base);
  *(float4*)(hf + base) = v;
  long long row = base >> 10;
  int col = (int)(base & 1023);
  f16x4 b;
  b[0] = (f16)v.x; b[1] = (f16)v.y; b[2] = (f16)v.z; b[3] = (f16)v.w;
  *(f16x4*)(hx + row * 2048 + col) = b;
}

__global__ __launch_bounds__(256) void srl_finalize(const float* hf, const float* w, const float* b,
                                                    float* out, float* conf) {
  const int bid = blockIdx.x;
  if (bid < 4096) {
    long long base = ((long long)bid * 256 + threadIdx.x) * 4;
    *(float4*)(out + base) = *(const float4*)(hf + base);
  } else {
    const int row = (bid - 4096) * 4 + (threadIdx.x >> 6);
    const int lane = threadIdx.x & 63;
    const float* p = hf + (long long)row * 1024;
    float s = 0.f;
    for (int j = lane; j < 1024; j += 64) s += p[j] * w[j];
#pragma unroll
    for (int o = 32; o > 0; o >>= 1) s += __shfl_down(s, o);
    if (lane == 0) conf[row] = 1.f / (1.f + __expf(-(s + b[0])));
  }
}

// =====================================================================================
extern "C" void kernel_launch(void* const* d_in, const int* in_sizes, int n_in,
                              void* d_out, int out_size, void* d_ws, size_t ws_size,
                              hipStream_t stream) {
  (void)in_sizes; (void)n_in; (void)out_size; (void)ws_size;
  const float* in_hidden   = (const float*)d_in[0];
  const float* in_rule_emb = (const float*)d_in[1];
  const float* in_rsel_w   = (const float*)d_in[2];
  const float* in_rsel_b   = (const float*)d_in[3];
  const float* in_attn_wq  = (const float*)d_in[4];
  const float* in_attn_bq  = (const float*)d_in[5];
  const float* in_attn_wk  = (const float*)d_in[6];
  const float* in_attn_bk  = (const float*)d_in[7];
  const float* in_attn_wv  = (const float*)d_in[8];
  const float* in_attn_bv  = (const float*)d_in[9];
  const float* in_attn_wo  = (const float*)d_in[10];
  const float* in_attn_bo  = (const float*)d_in[11];
  const float* in_memory   = (const float*)d_in[12];
  const float* in_mq_w     = (const float*)d_in[13];
  const float* in_mq_b     = (const float*)d_in[14];
  const float* in_mk_w     = (const float*)d_in[15];
  const float* in_mk_b     = (const float*)d_in[16];
  const float* in_mv_w     = (const float*)d_in[17];
  const float* in_mv_b     = (const float*)d_in[18];
  const float* in_maq_w    = (const float*)d_in[19];
  const float* in_maq_b    = (const float*)d_in[20];
  const float* in_mak_w    = (const float*)d_in[21];
  const float* in_mak_b    = (const float*)d_in[22];
  const float* in_mav_w    = (const float*)d_in[23];
  const float* in_mav_b    = (const float*)d_in[24];
  const float* in_mao_w    = (const float*)d_in[25];
  const float* in_mao_b    = (const float*)d_in[26];
  const float* in_ra_w1    = (const float*)d_in[27];
  const float* in_ra_b1    = (const float*)d_in[28];
  const float* in_ln_s     = (const float*)d_in[29];
  const float* in_ln_b     = (const float*)d_in[30];
  const float* in_ra_w2    = (const float*)d_in[31];
  const float* in_ra_b2    = (const float*)d_in[32];
  const float* in_conf_w   = (const float*)d_in[33];
  const float* in_conf_b   = (const float*)d_in[34];

  char* ws = (char*)d_ws;
  size_t off = 0;
  auto alloc = [&](size_t bytes) -> void* {
    void* p = ws + off;
    off = (off + bytes + 255) & ~(size_t)255;
    return p;
  };
  f16* wt_qkvr    = (f16*)alloc(3584 * 1024 * 2);
  float* bias_qkvr= (float*)alloc(3584 * 4);
  f16* wt_attn_o  = (f16*)alloc(1048576 * 2);
  f16* wt_mq_comp = (f16*)alloc(1048576 * 2);
  float* bcomp    = (float*)alloc(1024 * 4);
  f16* wt_mattn_o = (f16*)alloc(1048576 * 2);
  f16* wt_ra1     = (f16*)alloc(2097152 * 2);
  f16* wt_ra2     = (f16*)alloc(1048576 * 2);
  f16* wt_remb    = (f16*)alloc(524288 * 2);
  f16* wt_mem_kv  = (f16*)alloc(2097152 * 2);
  f16* wt_mattn_k = (f16*)alloc(1048576 * 2);
  f16* wt_mattn_v = (f16*)alloc(1048576 * 2);
  f16* mem_h      = (f16*)alloc(1048576 * 2);
  f16* mk_h       = (f16*)alloc(1048576 * 2);
  f16* mv_h       = (f16*)alloc(1048576 * 2);
  f16* mak_h      = (f16*)alloc(1048576 * 2);
  f16* mavT_h     = (f16*)alloc(1048576 * 2);
  float* h_f      = (float*)alloc(4194304 * 4);
  f16* hx         = (f16*)alloc(8388608 * 2);
  f16* q_h        = (f16*)alloc(4194304 * 2);
  f16* k_h        = (f16*)alloc(4194304 * 2);
  f16* vT_h       = (f16*)alloc(4194304 * 2);
  f16* ctx_h      = (f16*)alloc(4194304 * 2);
  f16* u_h        = (f16*)alloc(4194304 * 2);
  char* arena     = (char*)alloc(16777216);
  float* logits_f = (float*)arena;
  f16* probs_h    = (f16*)(arena + 8388608);
  float* ra1_f    = (float*)arena;
  f16* mqw_nt     = (f16*)arena;
  f16* wmaq_t     = (f16*)(arena + 2097152);

  auto mkOut = [](int n0, const float* bias, const float* resid, float* Cf, int ldcf,
                  f16* Cb, int ldcb, int transV, long long sCb, long long sCh) {
    SrlOut o;
    o.n0 = n0; o.bias = bias; o.resid = resid; o.Cf = Cf; o.Cb = Cb;
    o.ldcf = ldcf; o.ldcb = ldcb; o.transV = transV; o.sCb = sCb; o.sCh = sCh;
    return o;
  };
  // pipelined 128x128 kernel (big fused projection only)
  auto runP = [&](int M, int N, int K, const f16* A, int lda, const f16* B, int ldb,
                  float alpha, SrlGemmArgs g) {
    g.A = A; g.B = B; g.M = M; g.N = N; g.K = K; g.lda = lda; g.ldb = ldb;
    g.sAb = 0; g.sAh = 0; g.sBb = 0; g.sBh = 0; g.alpha = alpha;
    dim3 grid(N / 128, M / 128, 1);
    hipLaunchKernelGGL(srl_gemm_p, grid, dim3(512), 0, stream, g);
  };
  // 64x64 DMA-staged kernel: all in-loop N<=1024 GEMMs (1024 blocks -> 4/CU, measured best)
  auto runS = [&](int M, int N, int K, const f16* A, int lda, const f16* B, int ldb,
                  float alpha, const float* bias, const float* resid, float* Cf, int ldcf,
                  f16* Cb, int ldcb, int transV) {
    SrlGemmArgs g{};
    g.nOuts = 1;
    g.out[0] = mkOut(0, bias, resid, Cf, ldcf, Cb, ldcb, transV, 0, 0);
    g.A = A; g.B = B; g.M = M; g.N = N; g.K = K; g.lda = lda; g.ldb = ldb;
    g.sAb = 0; g.sAh = 0; g.sBb = 0; g.sBh = 0; g.alpha = alpha;
    dim3 grid((N + 63) / 64, (M + 63) / 64, 1);
    hipLaunchKernelGGL((srl_gemm<64, 64, 4>), grid, dim3(256), 0, stream, g);
  };
  auto runSm = [&](int M, int N, int K, const f16* A, int lda, const f16* B, int ldb,
                   float alpha, SrlGemmArgs g) {
    g.A = A; g.B = B; g.M = M; g.N = N; g.K = K; g.lda = lda; g.ldb = ldb;
    g.sAb = 0; g.sAh = 0; g.sBb = 0; g.sBh = 0; g.alpha = alpha;
    dim3 grid((N + 63) / 64, (M + 63) / 64, 1);
    hipLaunchKernelGGL((srl_gemm<64, 64, 4>), grid, dim3(256), 0, stream, g);
  };

  // ---- one-time weight convert/transpose ----
  SrlTcArgs tc;
  int ts = 0;
  auto setent = [&](int i, const float* s, f16* d, int rows, int cols, int trans) {
    tc.e[i].src = s; tc.e[i].dst = d; tc.e[i].rows = rows; tc.e[i].cols = cols;
    tc.e[i].trans = trans; tc.e[i].tileStart = ts;
    ts += (rows / 32) * (cols / 32);
  };
  setent(0,  in_attn_wq, wt_qkvr + 512 * 1024, 1024, 1024, 1);
  setent(1,  in_attn_wk, wt_qkvr + 1536 * 1024, 1024, 1024, 1);
  setent(2,  in_attn_wv, wt_qkvr + 2560 * 1024, 1024, 1024, 1);
  setent(3,  in_rsel_w,  wt_qkvr, 1024, 512, 1);
  setent(4,  in_attn_wo, wt_attn_o, 1024, 1024, 1);
  setent(5,  in_mq_w,    mqw_nt, 1024, 1024, 0);
  setent(6,  in_maq_w,   wmaq_t, 1024, 1024, 1);
  setent(7,  in_mak_w,   wt_mattn_k, 1024, 1024, 1);
  setent(8,  in_mav_w,   wt_mattn_v, 1024, 1024, 1);
  setent(9,  in_mk_w,    wt_mem_kv, 1024, 1024, 1);
  setent(10, in_mv_w,    wt_mem_kv + 1048576, 1024, 1024, 1);
  setent(11, in_mao_w,   wt_mattn_o, 1024, 1024, 1);
  setent(12, in_ra_w1,   wt_ra1, 2048, 1024, 1);
  setent(13, in_ra_w2,   wt_ra2, 1024, 1024, 1);
  setent(14, in_rule_emb, wt_remb, 512, 1024, 1);
  setent(15, in_memory,  mem_h, 1024, 1024, 0);
  hipLaunchKernelGGL(srl_convert_weights, dim3(ts), dim3(256), 0, stream, tc);
  hipLaunchKernelGGL(srl_prep_bias, dim3(18), dim3(256), 0, stream,
                     in_rsel_b, in_attn_bq, in_attn_bk, in_attn_bv,
                     in_mq_b, in_maq_w, in_maq_b, bias_qkvr, bcomp);
  hipLaunchKernelGGL(srl_h_init, dim3(4096), dim3(256), 0, stream, in_hidden, h_f, hx);

  // ---- preamble GEMMs (M=1024, run once) ----
  {
    SrlGemmArgs g{};
    g.nOuts = 2;
    g.out[0] = mkOut(0, in_mk_b, nullptr, nullptr, 0, mk_h, 1024, 0, 0, 0);
    g.out[1] = mkOut(1024, in_mv_b, nullptr, nullptr, 0, mv_h, 1024, 0, 0, 0);
    runSm(1024, 2048, 1024, mem_h, 1024, wt_mem_kv, 1024, 1.f, g);
  }
  runS(1024, 1024, 1024, mk_h, 1024, wt_mattn_k, 1024, 1.f, in_mak_b, nullptr, nullptr, 0, mak_h, 1024, 0);
  runS(1024, 1024, 1024, mv_h, 1024, wt_mattn_v, 1024, 1.f, in_mav_b, nullptr, nullptr, 0, mavT_h, 0, 1);
  runS(1024, 1024, 1024, wmaq_t, 1024, mqw_nt, 1024, 1.f, nullptr, nullptr, nullptr, 0, wt_mq_comp, 1024, 0);

  const float kLog2e = 1.4426950408889634f;
  for (int step = 0; step < 3; ++step) {
    {  // fused rule-logits + Q + K + V projection: 128x128 pipelined, 896 blocks
      SrlGemmArgs g{};
      g.nOuts = 4;
      g.out[0] = mkOut(0,    bias_qkvr,        nullptr, logits_f, 512, nullptr, 0, 0, 0, 0);
      g.out[1] = mkOut(512,  bias_qkvr + 512,  nullptr, nullptr, 0, q_h, 1024, 0, 0, 0);
      g.out[2] = mkOut(1536, bias_qkvr + 1536, nullptr, nullptr, 0, k_h, 1024, 0, 0, 0);
      g.out[3] = mkOut(2560, bias_qkvr + 2560, nullptr, nullptr, 0, vT_h, 0, 1, 0, 0);
      runP(4096, 3584, 1024, hx, 2048, wt_qkvr, 1024, 1.f, g);
    }
    hipLaunchKernelGGL(srl_softmax_rule, dim3(4096), dim3(256), 0, stream, logits_f, probs_h);
    runS(4096, 1024, 512, probs_h, 512, wt_remb, 512, 1.f, nullptr, nullptr, nullptr, 0, hx + 1024, 2048, 0);
    {
      SrlFlashArgs fa;
      fa.Q = q_h; fa.K = k_h; fa.VT = vT_h; fa.O = ctx_h;
      fa.sQb = 1048576; fa.sKb = 1048576; fa.sVb = 1048576; fa.scale = 0.125f * kLog2e;
      hipLaunchKernelGGL(srl_flash, dim3(512), dim3(256), 0, stream, fa);
    }
    runS(4096, 1024, 1024, ctx_h, 1024, wt_attn_o, 1024, 1.f, in_attn_bo, h_f, h_f, 1024, hx, 2048, 0);
    runS(4096, 1024, 1024, hx, 2048, wt_mq_comp, 1024, 1.f, bcomp, nullptr, nullptr, 0, k_h, 1024, 0);
    {
      SrlFlashArgs fa;
      fa.Q = k_h; fa.K = mak_h; fa.VT = mavT_h; fa.O = ctx_h;
      fa.sQb = 1048576; fa.sKb = 0; fa.sVb = 0; fa.scale = 0.125f * kLog2e;
      hipLaunchKernelGGL(srl_flash, dim3(512), dim3(256), 0, stream, fa);
    }
    runS(4096, 1024, 1024, ctx_h, 1024, wt_mattn_o, 1024, 1.f, in_mao_b, h_f, h_f, 1024, hx, 2048, 0);
    runS(4096, 1024, 2048, hx, 2048, wt_ra1, 2048, 1.f, in_ra_b1, nullptr, ra1_f, 1024, nullptr, 0, 0);
    hipLaunchKernelGGL(srl_ln_gelu, dim3(4096), dim3(256), 0, stream, ra1_f, in_ln_s, in_ln_b, u_h);
    runS(4096, 1024, 1024, u_h, 1024, wt_ra2, 1024, 1.f, in_ra_b2, h_f, h_f, 1024, hx, 2048, 0);
  }

  hipLaunchKernelGGL(srl_finalize, dim3(5120), dim3(256), 0, stream, h_f, in_conf_w, in_conf_b,
                     (float*)d_out, (float*)d_out + 4194304);
}

// Round 10
// 1042.096 us; speedup vs baseline: 1.8504x; 1.0655x over previous
//
#include <hip/hip_runtime.h>
#include <stdint.h>

typedef _Float16 f16;
typedef __attribute__((ext_vector_type(4))) float floatx4;
typedef __attribute__((ext_vector_type(8))) f16   f16x8;
typedef __attribute__((ext_vector_type(4))) f16   f16x4;

#define GLD_LDS16(gp, lp)                                                                      \
  __builtin_amdgcn_global_load_lds((const __attribute__((address_space(1))) void*)(uintptr_t)(gp), \
                                   (__attribute__((address_space(3))) void*)(uintptr_t)(lp), 16, 0, 0)

// ---------------- generalized f16 MFMA GEMM: C = alpha*A@B^T (+bias)(+resid) ----------------
struct SrlOut {
  int n0;
  const float* bias;
  const float* resid;
  float* Cf; f16* Cb;
  int ldcf, ldcb, transV;
  long long sCb, sCh;
};
struct SrlGemmArgs {
  const f16* A; const f16* B;
  int M, N, K, lda, ldb;
  long long sAb, sAh, sBb, sBh;
  float alpha;
  int nOuts;
  SrlOut out[4];
};

// 64x64 single-buffer DMA-staged kernel: 1024 blocks -> 4 blocks/CU, 16 waves/CU.
// MEASURED OPTIMUM across the full r0..r8 ablation matrix. Likely HBM-bound on the fp32
// residual stream (42MB/dispatch ~ 24us at 1.75TB/s = measured dur), which explains why
// every compute-side restructure (pipelining/BK/reg-stage/no-LDS) was neutral-to-negative.
template<int BM, int BN, int MINW>
__global__ __launch_bounds__(256, MINW) void srl_gemm(SrlGemmArgs g) {
  constexpr int BK = 64;
  constexpr int ACH = BM / 32;
  constexpr int BCH = BN / 32;
  constexpr int MI  = 2;
  constexpr int NI  = 2;
  __shared__ f16 As[BM * BK];
  __shared__ f16 Bs[BN * BK];
  const int tid  = threadIdx.x;
  const int wid  = tid >> 6;
  const int lane = tid & 63;

  const int gx = gridDim.x;
  const int NT = gx * gridDim.y;
  const int L  = blockIdx.y * gx + blockIdx.x;
  const int W  = ((NT & 7) == 0) ? ((L & 7) * (NT >> 3) + (L >> 3)) : L;
  const int tn = (W % gx) * BN;
  const int tm = (W / gx) * BM;

  const f16* Ab = g.A + (long long)tm * g.lda;
  const f16* Bb = g.B + (long long)tn * g.ldb;
  const int maxAr = g.M - 1 - tm;
  const int maxBr = g.N - 1 - tn;

  // staging maps; LDS layout xor-swizzled: elem (row,k) at row*64 + (((k>>3)+row)&7)*8 + (k&7)
  int aR[ACH], aO[ACH];
#pragma unroll
  for (int i = 0; i < ACH; ++i) {
    int e = wid * (BM * 16) + i * 512 + lane * 8;
    int r = e >> 6, s = (e >> 3) & 7;
    aR[i] = (r <= maxAr) ? r : maxAr;
    aO[i] = ((s - r) & 7) * 8;
  }
  int bR[BCH], bO[BCH];
#pragma unroll
  for (int i = 0; i < BCH; ++i) {
    int e = wid * (BN * 16) + i * 512 + lane * 8;
    int r = e >> 6, s = (e >> 3) & 7;
    bR[i] = (r <= maxBr) ? r : maxBr;
    bO[i] = ((s - r) & 7) * 8;
  }
  f16* lA = As + wid * (BM * 16);
  f16* lB = Bs + wid * (BN * 16);

  floatx4 acc[MI][NI];
#pragma unroll
  for (int a = 0; a < MI; ++a)
#pragma unroll
    for (int b = 0; b < NI; ++b) {
      acc[a][b][0] = 0.f; acc[a][b][1] = 0.f; acc[a][b][2] = 0.f; acc[a][b][3] = 0.f;
    }

  const int wm = (wid & 1) * 32;
  const int wn = (wid >> 1) * 32;
  const int lm = lane & 15;
  const int quad = lane >> 4;

  for (int k0 = 0; k0 < g.K; k0 += BK) {
    __syncthreads();
#pragma unroll
    for (int i = 0; i < ACH; ++i)
      GLD_LDS16(Ab + (long long)aR[i] * g.lda + (k0 + aO[i]), lA + i * 512);
#pragma unroll
    for (int i = 0; i < BCH; ++i)
      GLD_LDS16(Bb + (long long)bR[i] * g.ldb + (k0 + bO[i]), lB + i * 512);
    __syncthreads();
#pragma unroll
    for (int ks = 0; ks < 2; ++ks) {
      f16x8 af[MI], bfr[NI];
#pragma unroll
      for (int mi = 0; mi < MI; ++mi) {
        int row = wm + mi * 16 + lm;
        int sg = ((ks * 4 + quad) + row) & 7;
        af[mi] = *(const f16x8*)(As + row * 64 + sg * 8);
      }
#pragma unroll
      for (int ni = 0; ni < NI; ++ni) {
        int row = wn + ni * 16 + lm;
        int sg = ((ks * 4 + quad) + row) & 7;
        bfr[ni] = *(const f16x8*)(Bs + row * 64 + sg * 8);
      }
#pragma unroll
      for (int mi = 0; mi < MI; ++mi)
#pragma unroll
        for (int ni = 0; ni < NI; ++ni)
          acc[mi][ni] = __builtin_amdgcn_mfma_f32_16x16x32_f16(af[mi], bfr[ni], acc[mi][ni], 0, 0, 0);
    }
  }

  int oi = 0;
  for (int j = 1; j < g.nOuts; ++j)
    if (tn >= g.out[j].n0) oi = j;
  const SrlOut O = g.out[oi];
#pragma unroll
  for (int mi = 0; mi < MI; ++mi) {
#pragma unroll
    for (int r = 0; r < 4; ++r) {
      int m = tm + wm + mi * 16 + quad * 4 + r;
      if (m >= g.M) continue;
#pragma unroll
      for (int ni = 0; ni < NI; ++ni) {
        int n = tn + wn + ni * 16 + lm;
        if (n >= g.N) continue;
        int nl = n - O.n0;
        float v = acc[mi][ni][r] * g.alpha;
        if (O.bias)  v += O.bias[nl];
        if (O.resid) v += O.resid[(long long)m * O.ldcf + nl];
        if (O.Cf)    O.Cf[(long long)m * O.ldcf + nl] = v;
        if (O.Cb) {
          long long idx = O.transV
              ? ((long long)(m >> 10) * 1048576 + (long long)nl * 1024 + (m & 1023))
              : ((long long)m * O.ldcb + nl);
          O.Cb[idx] = (f16)v;
        }
      }
    }
  }
}

// ---------------- pipelined 128x128 8-wave GEMM (2-phase, 2-buffer; measured 58-60us) -------
// Big fused projection only. 64KB LDS -> 2 blocks/CU: cross-block TLP covers the per-step
// drain; within-block the next tile's loads are issued before compute.
__global__ __launch_bounds__(512, 4) void srl_gemm_p(SrlGemmArgs g) {
  __shared__ f16 As[2][8192];
  __shared__ f16 Bs[2][8192];
  const int tid  = threadIdx.x;
  const int wid  = tid >> 6;        // 0..7
  const int lane = tid & 63;

  const int gx  = gridDim.x;
  const int NTt = gx * gridDim.y;
  const int L   = blockIdx.y * gx + blockIdx.x;
  const int W   = ((NTt & 7) == 0) ? ((L & 7) * (NTt >> 3) + (L >> 3)) : L;
  const int tn  = (W % gx) * 128;
  const int tm  = (W / gx) * 128;

  const f16* Ab = g.A + (long long)tm * g.lda;
  const f16* Bb = g.B + (long long)tn * g.ldb;

  // staging maps; LDS layout xor-swizzled: elem (row,k) at row*64 + (((k>>3)+row)&7)*8 + (k&7)
  int aR[2], aO[2];
#pragma unroll
  for (int i = 0; i < 2; ++i) {
    int e = wid * 1024 + i * 512 + lane * 8;
    int r = e >> 6, s = (e >> 3) & 7;
    aR[i] = r; aO[i] = ((s - r) & 7) * 8;
  }

  const int wm = (wid >> 1) * 32;   // 4 wave-rows
  const int wn = (wid & 1) * 64;    // 2 wave-cols
  const int lm = lane & 15;
  const int quad = lane >> 4;

  floatx4 acc[2][4];
#pragma unroll
  for (int a = 0; a < 2; ++a)
#pragma unroll
    for (int b = 0; b < 4; ++b) {
      acc[a][b][0] = 0.f; acc[a][b][1] = 0.f; acc[a][b][2] = 0.f; acc[a][b][3] = 0.f;
    }

  const int nk = g.K >> 6;

  auto stage = [&](int kt, int bsel) {
    const int k0 = kt << 6;
    f16* lA = &As[bsel][0] + wid * 1024;
    f16* lB = &Bs[bsel][0] + wid * 1024;
#pragma unroll
    for (int i = 0; i < 2; ++i)
      GLD_LDS16(Ab + (long long)aR[i] * g.lda + (k0 + aO[i]), lA + i * 512);
#pragma unroll
    for (int i = 0; i < 2; ++i)
      GLD_LDS16(Bb + (long long)aR[i] * g.ldb + (k0 + aO[i]), lB + i * 512);
  };

  stage(0, 0);
  asm volatile("s_waitcnt vmcnt(0)" ::: "memory");
  __builtin_amdgcn_s_barrier();

  auto onestep = [&](int t, int cb) {
    if (t + 1 < nk) stage(t + 1, cb ^ 1);        // issue next-tile loads FIRST
    asm volatile("" ::: "memory");
    const f16* Asb = &As[cb][0];
    const f16* Bsb = &Bs[cb][0];
#pragma unroll
    for (int ks = 0; ks < 2; ++ks) {
      f16x8 af[2], bfr[4];
#pragma unroll
      for (int mi = 0; mi < 2; ++mi) {
        int row = wm + mi * 16 + lm;
        int sg = ((ks * 4 + quad) + row) & 7;
        af[mi] = *(const f16x8*)(Asb + row * 64 + sg * 8);
      }
#pragma unroll
      for (int ni = 0; ni < 4; ++ni) {
        int row = wn + ni * 16 + lm;
        int sg = ((ks * 4 + quad) + row) & 7;
        bfr[ni] = *(const f16x8*)(Bsb + row * 64 + sg * 8);
      }
#pragma unroll
      for (int mi = 0; mi < 2; ++mi)
#pragma unroll
        for (int ni = 0; ni < 4; ++ni)
          acc[mi][ni] = __builtin_amdgcn_mfma_f32_16x16x32_f16(af[mi], bfr[ni], acc[mi][ni], 0, 0, 0);
    }
    asm volatile("s_waitcnt vmcnt(0) lgkmcnt(0)" ::: "memory");
    __builtin_amdgcn_s_barrier();
  };

  for (int t = 0; t < nk; t += 2) {   // nk is even for all routed shapes
    onestep(t, 0);
    onestep(t + 1, 1);
  }

  int oi = 0;
  for (int j = 1; j < g.nOuts; ++j)
    if (tn >= g.out[j].n0) oi = j;
  const SrlOut O = g.out[oi];
#pragma unroll
  for (int mi = 0; mi < 2; ++mi) {
#pragma unroll
    for (int r = 0; r < 4; ++r) {
      int m = tm + wm + mi * 16 + quad * 4 + r;
#pragma unroll
      for (int ni = 0; ni < 4; ++ni) {
        int n = tn + wn + ni * 16 + lm;
        int nl = n - O.n0;
        float v = acc[mi][ni][r] * g.alpha;
        if (O.bias)  v += O.bias[nl];
        if (O.resid) v += O.resid[(long long)m * O.ldcf + nl];
        if (O.Cf)    O.Cf[(long long)m * O.ldcf + nl] = v;
        if (O.Cb) {
          long long idx = O.transV
              ? ((long long)(m >> 10) * 1048576 + (long long)nl * 1024 + (m & 1023))
              : ((long long)m * O.ldcb + nl);
          O.Cb[idx] = (f16)v;
        }
      }
    }
  }
}

// ---------------- fused flash attention: per-block (b,head,qtile=128), S=1024, d=64 ----------
// K/V staging is T14 async-split (global->reg->LDS): loads for tile t+1 are issued at the TOP
// of tile t's compute, and written to LDS between two barriers after compute. (r4-measured win;
// T14 pays here because the compute phase covers the latency.)
struct SrlFlashArgs {
  const f16* Q; const f16* K; const f16* VT; f16* O;
  long long sQb, sKb, sVb;
  float scale;   // includes log2(e)
};

__global__ __launch_bounds__(256, 2) void srl_flash(SrlFlashArgs a) {
  __shared__ f16 Qs[8192];
  __shared__ f16 Ks[8192];
  __shared__ f16 VTs[8192];
  __shared__ f16 Ps[4][4096];
  const int tid = threadIdx.x, wid = tid >> 6, lane = tid & 63;
  const int quad = lane >> 4, c = lane & 15;
  const int L = blockIdx.x;
  const int bh = (L & 7) + ((L >> 6) << 3);
  const int qt = (L >> 3) & 7;
  const int b = bh >> 4, h = bh & 15;
  const f16* Qg = a.Q + (long long)b * a.sQb + (long long)qt * 131072 + h * 64;
  const f16* Kg = a.K + (long long)b * a.sKb + h * 64;
  const f16* Vg = a.VT + (long long)b * a.sVb + (long long)h * 65536;
  f16* Og = a.O + (long long)b * 1048576 + (long long)qt * 131072 + h * 64;

  int rRow[4], rOff[4];
#pragma unroll
  for (int i = 0; i < 4; ++i) {
    int e = wid * 2048 + i * 512 + lane * 8;
    int r = e >> 6, gL = (e >> 3) & 7;
    rRow[i] = r; rOff[i] = ((gL - r) & 7) * 8;
  }
  int vRow[4], vOff[4];
#pragma unroll
  for (int i = 0; i < 4; ++i) {
    int e = wid * 2048 + i * 512 + lane * 8;
    int d = e >> 7, gL = (e >> 3) & 15;
    vRow[i] = d; vOff[i] = ((gL - (d & 7)) & 15) * 8;
  }

  // prologue: Q via global_load_lds; K/V tile 0 via reg-stage; one barrier covers all
#pragma unroll
  for (int i = 0; i < 4; ++i)
    GLD_LDS16(Qg + (long long)rRow[i] * 1024 + rOff[i], Qs + wid * 2048 + i * 512);

  f16x8 kreg[4], vreg[4];
#pragma unroll
  for (int i = 0; i < 4; ++i)
    kreg[i] = *(const f16x8*)(Kg + (long long)rRow[i] * 1024 + rOff[i]);
#pragma unroll
  for (int i = 0; i < 4; ++i)
    vreg[i] = *(const f16x8*)(Vg + (long long)vRow[i] * 1024 + vOff[i]);
#pragma unroll
  for (int i = 0; i < 4; ++i)
    *(f16x8*)(Ks + wid * 2048 + i * 512 + lane * 8) = kreg[i];
#pragma unroll
  for (int i = 0; i < 4; ++i)
    *(f16x8*)(VTs + wid * 2048 + i * 512 + lane * 8) = vreg[i];
  __syncthreads();

  const int wq = wid * 32;
  f16x8 qf[2][2];
#pragma unroll
  for (int nf = 0; nf < 2; ++nf)
#pragma unroll
    for (int ch = 0; ch < 2; ++ch) {
      int row = wq + nf * 16 + c;
      int slot = ((ch * 4 + quad) + row) & 7;
      f16x8 v = *(const f16x8*)(Qs + row * 64 + slot * 8);
      f16 sc = (f16)a.scale;
#pragma unroll
      for (int j = 0; j < 8; ++j) v[j] = v[j] * sc;
      qf[nf][ch] = v;
    }

  float l_s[2] = {0.f, 0.f};
  floatx4 Oa[2][4];
#pragma unroll
  for (int nf = 0; nf < 2; ++nf)
#pragma unroll
    for (int no = 0; no < 4; ++no) {
      Oa[nf][no][0] = 0.f; Oa[nf][no][1] = 0.f; Oa[nf][no][2] = 0.f; Oa[nf][no][3] = 0.f;
    }

  for (int t = 0; t < 8; ++t) {
    // issue next tile's K/V loads into registers FIRST — they land during this tile's compute
    if (t < 7) {
#pragma unroll
      for (int i = 0; i < 4; ++i)
        kreg[i] = *(const f16x8*)(Kg + (long long)((t + 1) * 128 + rRow[i]) * 1024 + rOff[i]);
#pragma unroll
      for (int i = 0; i < 4; ++i)
        vreg[i] = *(const f16x8*)(Vg + (long long)vRow[i] * 1024 + ((t + 1) * 128 + vOff[i]));
    }

    floatx4 sT[2][8];
#pragma unroll
    for (int nf = 0; nf < 2; ++nf)
#pragma unroll
      for (int mf = 0; mf < 8; ++mf) {
        sT[nf][mf][0] = 0.f; sT[nf][mf][1] = 0.f; sT[nf][mf][2] = 0.f; sT[nf][mf][3] = 0.f;
      }
    __builtin_amdgcn_s_setprio(1);
#pragma unroll
    for (int ch = 0; ch < 2; ++ch)
#pragma unroll
      for (int mf = 0; mf < 8; ++mf) {
        int key = mf * 16 + c;
        int slot = ((ch * 4 + quad) + key) & 7;
        f16x8 kf = *(const f16x8*)(Ks + key * 64 + slot * 8);
        sT[0][mf] = __builtin_amdgcn_mfma_f32_16x16x32_f16(kf, qf[0][ch], sT[0][mf], 0, 0, 0);
        sT[1][mf] = __builtin_amdgcn_mfma_f32_16x16x32_f16(kf, qf[1][ch], sT[1][mf], 0, 0, 0);
      }
    __builtin_amdgcn_s_setprio(0);

#pragma unroll
    for (int nf = 0; nf < 2; ++nf) {
      float lt = 0.f;
      const int q = nf * 16 + c;
#pragma unroll
      for (int mf = 0; mf < 8; ++mf) {
        f16x4 pk;
#pragma unroll
        for (int r = 0; r < 4; ++r) {
          float p = __builtin_amdgcn_exp2f(sT[nf][mf][r]);
          lt += p;
          pk[r] = (f16)p;
        }
        int kg = mf * 2 + (quad >> 1), sub = (quad & 1) * 4;
        int slot = (kg + (q & 7)) & 15;
        *(f16x4*)(Ps[wid] + q * 128 + slot * 8 + sub) = pk;
      }
      lt += __shfl_xor(lt, 16);
      lt += __shfl_xor(lt, 32);
      l_s[nf] += lt;
    }
#pragma unroll
    for (int cc = 0; cc < 4; ++cc) {
      f16x8 af[2];
#pragma unroll
      for (int nf = 0; nf < 2; ++nf) {
        int q = nf * 16 + c;
        int slot = ((cc * 4 + quad) + (q & 7)) & 15;
        af[nf] = *(const f16x8*)(Ps[wid] + q * 128 + slot * 8);
      }
      __builtin_amdgcn_s_setprio(1);
#pragma unroll
      for (int no = 0; no < 4; ++no) {
        int d = no * 16 + c;
        int slot = ((cc * 4 + quad) + (d & 7)) & 15;
        f16x8 vf = *(const f16x8*)(VTs + d * 128 + slot * 8);
        Oa[0][no] = __builtin_amdgcn_mfma_f32_16x16x32_f16(af[0], vf, Oa[0][no], 0, 0, 0);
        Oa[1][no] = __builtin_amdgcn_mfma_f32_16x16x32_f16(af[1], vf, Oa[1][no], 0, 0, 0);
      }
      __builtin_amdgcn_s_setprio(0);
    }

    // write the prefetched tile: barrier (all waves done reading t) -> ds_write -> barrier
    if (t < 7) {
      __syncthreads();
#pragma unroll
      for (int i = 0; i < 4; ++i)
        *(f16x8*)(Ks + wid * 2048 + i * 512 + lane * 8) = kreg[i];
#pragma unroll
      for (int i = 0; i < 4; ++i)
        *(f16x8*)(VTs + wid * 2048 + i * 512 + lane * 8) = vreg[i];
      __syncthreads();
    }
  }

#pragma unroll
  for (int nf = 0; nf < 2; ++nf)
#pragma unroll
    for (int r = 0; r < 4; ++r) {
      float li = 1.f / __shfl(l_s[nf], quad * 4 + r);
      int qrow = wq + nf * 16 + quad * 4 + r;
#pragma unroll
      for (int no = 0; no < 4; ++no)
        Qs[qrow * 64 + no * 16 + c] = (f16)(Oa[nf][no][r] * li);
    }
  __syncthreads();
#pragma unroll
  for (int i = 0; i < 4; ++i) {
    int e = wid * 2048 + i * 512 + lane * 8;
    int row = e >> 6, col = e & 63;
    *(f16x8*)(Og + (long long)row * 1024 + col) = *(const f16x8*)(Qs + e);
  }
}

// ---------------- rule softmax: fp32 logits [rows,512] -> f16 probs ----------------
__global__ __launch_bounds__(256) void srl_softmax_rule(const float* logits, f16* probs) {
  __shared__ float red[16];
  const long long row = blockIdx.x;
  const float* p = logits + row * 512;
  const int tid = threadIdx.x;
  float v0 = p[tid], v1 = p[tid + 256];
  float mx = fmaxf(v0, v1);
#pragma unroll
  for (int o = 32; o > 0; o >>= 1) mx = fmaxf(mx, __shfl_down(mx, o));
  const int wid = tid >> 6, lane = tid & 63;
  if (lane == 0) red[wid] = mx;
  __syncthreads();
  if (tid == 0) red[8] = fmaxf(fmaxf(red[0], red[1]), fmaxf(red[2], red[3]));
  __syncthreads();
  mx = red[8];
  float e0 = __expf(v0 - mx), e1 = __expf(v1 - mx);
  float s = e0 + e1;
#pragma unroll
  for (int o = 32; o > 0; o >>= 1) s += __shfl_down(s, o);
  if (lane == 0) red[wid + 4] = s;
  __syncthreads();
  if (tid == 0) red[9] = 1.f / (red[4] + red[5] + red[6] + red[7]);
  __syncthreads();
  const float inv = red[9];
  probs[row * 512 + tid] = (f16)(e0 * inv);
  probs[row * 512 + tid + 256] = (f16)(e1 * inv);
}

// ---------------- LayerNorm + exact GELU: fp32 [rows,1024] -> f16 ----------------
__global__ __launch_bounds__(256) void srl_ln_gelu(const float* x, const float* gam, const float* bet, f16* out) {
  __shared__ float red[16];
  const long long row = blockIdx.x;
  const float* p = x + row * 1024;
  const int tid = threadIdx.x;
  float4 xv = *(const float4*)(p + tid * 4);
  float v[4] = {xv.x, xv.y, xv.z, xv.w};
  float s = v[0] + v[1] + v[2] + v[3];
  float s2 = v[0] * v[0] + v[1] * v[1] + v[2] * v[2] + v[3] * v[3];
#pragma unroll
  for (int o = 32; o > 0; o >>= 1) { s += __shfl_down(s, o); s2 += __shfl_down(s2, o); }
  const int wid = tid >> 6, lane = tid & 63;
  if (lane == 0) { red[wid] = s; red[wid + 4] = s2; }
  __syncthreads();
  if (tid == 0) {
    float ts = red[0] + red[1] + red[2] + red[3];
    float ts2 = red[4] + red[5] + red[6] + red[7];
    float mu = ts * (1.f / 1024.f);
    float var = ts2 * (1.f / 1024.f) - mu * mu;
    red[8] = mu;
    red[9] = rsqrtf(var + 1e-5f);
  }
  __syncthreads();
  const float mu = red[8], rstd = red[9];
  f16x4 o4;
#pragma unroll
  for (int i = 0; i < 4; ++i) {
    int c = tid * 4 + i;
    float t = (v[i] - mu) * rstd * gam[c] + bet[c];
    float ge = 0.5f * t * (1.f + erff(t * 0.70710678118654752f));
    o4[i] = (f16)ge;
  }
  *(f16x4*)(out + row * 1024 + tid * 4) = o4;
}

// ---------------- batched weight convert (+optional transpose) fp32 -> f16 ----------------
struct SrlTcEnt { const float* src; f16* dst; int rows, cols, trans, tileStart; };
struct SrlTcArgs { SrlTcEnt e[16]; };

__global__ __launch_bounds__(256) void srl_convert_weights(SrlTcArgs a) {
  __shared__ float t[32][33];
  const int bt = blockIdx.x;
  int ei = 0;
#pragma unroll
  for (int j = 1; j < 16; ++j)
    if (bt >= a.e[j].tileStart) ei = j;
  SrlTcEnt E = a.e[ei];
  const int lt = bt - E.tileStart;
  const int tcols = E.cols >> 5;
  const int tr = lt / tcols;
  const int tc = lt - tr * tcols;
  const int r = threadIdx.x >> 5;
  const int c = threadIdx.x & 31;
  if (!E.trans) {
#pragma unroll
    for (int p = 0; p < 4; ++p) {
      long long rr = tr * 32 + r + p * 8;
      long long idx = rr * E.cols + tc * 32 + c;
      E.dst[idx] = (f16)E.src[idx];
    }
  } else {
#pragma unroll
    for (int p = 0; p < 4; ++p)
      t[r + p * 8][c] = E.src[(long long)(tr * 32 + r + p * 8) * E.cols + tc * 32 + c];
    __syncthreads();
#pragma unroll
    for (int p = 0; p < 4; ++p)
      E.dst[(long long)(tc * 32 + r + p * 8) * E.rows + tr * 32 + c] = (f16)t[c][r + p * 8];
  }
}

// ---------------- fused bias prep ----------------
__global__ __launch_bounds__(256) void srl_prep_bias(const float* rsel_b, const float* bq,
                                                     const float* bk, const float* bv,
                                                     const float* bmq, const float* maq_w,
                                                     const float* bmaq,
                                                     float* bias_qkvr, float* bcomp) {
  int i = blockIdx.x * 256 + threadIdx.x;
  if (i < 3584) {
    float v;
    if (i < 512) v = rsel_b[i];
    else if (i < 1536) v = bq[i - 512];
    else if (i < 2560) v = bk[i - 1536];
    else v = bv[i - 2560];
    bias_qkvr[i] = v;
  } else if (i < 3584 + 1024) {
    int m = i - 3584;
    float s = bmaq[m];
    for (int t = 0; t < 1024; ++t) s += bmq[t] * maq_w[(long long)t * 1024 + m];
    bcomp[m] = s;
  }
}

// ---------------- h init / confidence ----------------
__global__ __launch_bounds__(256) void srl_h_init(const float* hidden, float* hf, f16* hx) {
  long long base = ((long long)blockIdx.x * 256 + threadIdx.x) * 4;
  float4 v = *(const float4*)(hidden + base);
  *(float4*)(hf + base) = v;
  long long row = base >> 10;
  int col = (int)(base & 1023);
  f16x4 b;
  b[0] = (f16)v.x; b[1] = (f16)v.y; b[2] = (f16)v.z; b[3] = (f16)v.w;
  *(f16x4*)(hx + row * 2048 + col) = b;
}

// confidence only: the final ra2 GEMM writes h directly into d_out, so no copy pass needed.
__global__ __launch_bounds__(256) void srl_conf(const float* hout, const float* w, const float* b,
                                                float* conf) {
  const int row = blockIdx.x * 4 + (threadIdx.x >> 6);
  const int lane = threadIdx.x & 63;
  const float* p = hout + (long long)row * 1024;
  float s = 0.f;
  for (int j = lane; j < 1024; j += 64) s += p[j] * w[j];
#pragma unroll
  for (int o = 32; o > 0; o >>= 1) s += __shfl_down(s, o);
  if (lane == 0) conf[row] = 1.f / (1.f + __expf(-(s + b[0])));
}

// =====================================================================================
extern "C" void kernel_launch(void* const* d_in, const int* in_sizes, int n_in,
                              void* d_out, int out_size, void* d_ws, size_t ws_size,
                              hipStream_t stream) {
  (void)in_sizes; (void)n_in; (void)out_size; (void)ws_size;
  const float* in_hidden   = (const float*)d_in[0];
  const float* in_rule_emb = (const float*)d_in[1];
  const float* in_rsel_w   = (const float*)d_in[2];
  const float* in_rsel_b   = (const float*)d_in[3];
  const float* in_attn_wq  = (const float*)d_in[4];
  const float* in_attn_bq  = (const float*)d_in[5];
  const float* in_attn_wk  = (const float*)d_in[6];
  const float* in_attn_bk  = (const float*)d_in[7];
  const float* in_attn_wv  = (const float*)d_in[8];
  const float* in_attn_bv  = (const float*)d_in[9];
  const float* in_attn_wo  = (const float*)d_in[10];
  const float* in_attn_bo  = (const float*)d_in[11];
  const float* in_memory   = (const float*)d_in[12];
  const float* in_mq_w     = (const float*)d_in[13];
  const float* in_mq_b     = (const float*)d_in[14];
  const float* in_mk_w     = (const float*)d_in[15];
  const float* in_mk_b     = (const float*)d_in[16];
  const float* in_mv_w     = (const float*)d_in[17];
  const float* in_mv_b     = (const float*)d_in[18];
  const float* in_maq_w    = (const float*)d_in[19];
  const float* in_maq_b    = (const float*)d_in[20];
  const float* in_mak_w    = (const float*)d_in[21];
  const float* in_mak_b    = (const float*)d_in[22];
  const float* in_mav_w    = (const float*)d_in[23];
  const float* in_mav_b    = (const float*)d_in[24];
  const float* in_mao_w    = (const float*)d_in[25];
  const float* in_mao_b    = (const float*)d_in[26];
  const float* in_ra_w1    = (const float*)d_in[27];
  const float* in_ra_b1    = (const float*)d_in[28];
  const float* in_ln_s     = (const float*)d_in[29];
  const float* in_ln_b     = (const float*)d_in[30];
  const float* in_ra_w2    = (const float*)d_in[31];
  const float* in_ra_b2    = (const float*)d_in[32];
  const float* in_conf_w   = (const float*)d_in[33];
  const float* in_conf_b   = (const float*)d_in[34];

  char* ws = (char*)d_ws;
  size_t off = 0;
  auto alloc = [&](size_t bytes) -> void* {
    void* p = ws + off;
    off = (off + bytes + 255) & ~(size_t)255;
    return p;
  };
  f16* wt_qkvr    = (f16*)alloc(3584 * 1024 * 2);
  float* bias_qkvr= (float*)alloc(3584 * 4);
  f16* wt_attn_o  = (f16*)alloc(1048576 * 2);
  f16* wt_mq_comp = (f16*)alloc(1048576 * 2);
  float* bcomp    = (float*)alloc(1024 * 4);
  f16* wt_mattn_o = (f16*)alloc(1048576 * 2);
  f16* wt_ra1     = (f16*)alloc(2097152 * 2);
  f16* wt_ra2     = (f16*)alloc(1048576 * 2);
  f16* wt_remb    = (f16*)alloc(524288 * 2);
  f16* wt_mem_kv  = (f16*)alloc(2097152 * 2);
  f16* wt_mattn_k = (f16*)alloc(1048576 * 2);
  f16* wt_mattn_v = (f16*)alloc(1048576 * 2);
  f16* mem_h      = (f16*)alloc(1048576 * 2);
  f16* mk_h       = (f16*)alloc(1048576 * 2);
  f16* mv_h       = (f16*)alloc(1048576 * 2);
  f16* mak_h      = (f16*)alloc(1048576 * 2);
  f16* mavT_h     = (f16*)alloc(1048576 * 2);
  float* h_f      = (float*)alloc(4194304 * 4);
  f16* hx         = (f16*)alloc(8388608 * 2);
  f16* q_h        = (f16*)alloc(4194304 * 2);
  f16* k_h        = (f16*)alloc(4194304 * 2);
  f16* vT_h       = (f16*)alloc(4194304 * 2);
  f16* ctx_h      = (f16*)alloc(4194304 * 2);
  f16* u_h        = (f16*)alloc(4194304 * 2);
  char* arena     = (char*)alloc(16777216);
  float* logits_f = (float*)arena;
  f16* probs_h    = (f16*)(arena + 8388608);
  float* ra1_f    = (float*)arena;
  f16* mqw_nt     = (f16*)arena;
  f16* wmaq_t     = (f16*)(arena + 2097152);

  auto mkOut = [](int n0, const float* bias, const float* resid, float* Cf, int ldcf,
                  f16* Cb, int ldcb, int transV, long long sCb, long long sCh) {
    SrlOut o;
    o.n0 = n0; o.bias = bias; o.resid = resid; o.Cf = Cf; o.Cb = Cb;
    o.ldcf = ldcf; o.ldcb = ldcb; o.transV = transV; o.sCb = sCb; o.sCh = sCh;
    return o;
  };
  // pipelined 128x128 kernel (big fused projection only)
  auto runP = [&](int M, int N, int K, const f16* A, int lda, const f16* B, int ldb,
                  float alpha, SrlGemmArgs g) {
    g.A = A; g.B = B; g.M = M; g.N = N; g.K = K; g.lda = lda; g.ldb = ldb;
    g.sAb = 0; g.sAh = 0; g.sBb = 0; g.sBh = 0; g.alpha = alpha;
    dim3 grid(N / 128, M / 128, 1);
    hipLaunchKernelGGL(srl_gemm_p, grid, dim3(512), 0, stream, g);
  };
  // 64x64 DMA-staged kernel: all in-loop N<=1024 GEMMs (1024 blocks -> 4/CU, measured best)
  auto runS = [&](int M, int N, int K, const f16* A, int lda, const f16* B, int ldb,
                  float alpha, const float* bias, const float* resid, float* Cf, int ldcf,
                  f16* Cb, int ldcb, int transV) {
    SrlGemmArgs g{};
    g.nOuts = 1;
    g.out[0] = mkOut(0, bias, resid, Cf, ldcf, Cb, ldcb, transV, 0, 0);
    g.A = A; g.B = B; g.M = M; g.N = N; g.K = K; g.lda = lda; g.ldb = ldb;
    g.sAb = 0; g.sAh = 0; g.sBb = 0; g.sBh = 0; g.alpha = alpha;
    dim3 grid((N + 63) / 64, (M + 63) / 64, 1);
    hipLaunchKernelGGL((srl_gemm<64, 64, 4>), grid, dim3(256), 0, stream, g);
  };
  auto runSm = [&](int M, int N, int K, const f16* A, int lda, const f16* B, int ldb,
                   float alpha, SrlGemmArgs g) {
    g.A = A; g.B = B; g.M = M; g.N = N; g.K = K; g.lda = lda; g.ldb = ldb;
    g.sAb = 0; g.sAh = 0; g.sBb = 0; g.sBh = 0; g.alpha = alpha;
    dim3 grid((N + 63) / 64, (M + 63) / 64, 1);
    hipLaunchKernelGGL((srl_gemm<64, 64, 4>), grid, dim3(256), 0, stream, g);
  };

  // ---- one-time weight convert/transpose ----
  SrlTcArgs tc;
  int ts = 0;
  auto setent = [&](int i, const float* s, f16* d, int rows, int cols, int trans) {
    tc.e[i].src = s; tc.e[i].dst = d; tc.e[i].rows = rows; tc.e[i].cols = cols;
    tc.e[i].trans = trans; tc.e[i].tileStart = ts;
    ts += (rows / 32) * (cols / 32);
  };
  setent(0,  in_attn_wq, wt_qkvr + 512 * 1024, 1024, 1024, 1);
  setent(1,  in_attn_wk, wt_qkvr + 1536 * 1024, 1024, 1024, 1);
  setent(2,  in_attn_wv, wt_qkvr + 2560 * 1024, 1024, 1024, 1);
  setent(3,  in_rsel_w,  wt_qkvr, 1024, 512, 1);
  setent(4,  in_attn_wo, wt_attn_o, 1024, 1024, 1);
  setent(5,  in_mq_w,    mqw_nt, 1024, 1024, 0);
  setent(6,  in_maq_w,   wmaq_t, 1024, 1024, 1);
  setent(7,  in_mak_w,   wt_mattn_k, 1024, 1024, 1);
  setent(8,  in_mav_w,   wt_mattn_v, 1024, 1024, 1);
  setent(9,  in_mk_w,    wt_mem_kv, 1024, 1024, 1);
  setent(10, in_mv_w,    wt_mem_kv + 1048576, 1024, 1024, 1);
  setent(11, in_mao_w,   wt_mattn_o, 1024, 1024, 1);
  setent(12, in_ra_w1,   wt_ra1, 2048, 1024, 1);
  setent(13, in_ra_w2,   wt_ra2, 1024, 1024, 1);
  setent(14, in_rule_emb, wt_remb, 512, 1024, 1);
  setent(15, in_memory,  mem_h, 1024, 1024, 0);
  hipLaunchKernelGGL(srl_convert_weights, dim3(ts), dim3(256), 0, stream, tc);
  hipLaunchKernelGGL(srl_prep_bias, dim3(18), dim3(256), 0, stream,
                     in_rsel_b, in_attn_bq, in_attn_bk, in_attn_bv,
                     in_mq_b, in_maq_w, in_maq_b, bias_qkvr, bcomp);
  hipLaunchKernelGGL(srl_h_init, dim3(4096), dim3(256), 0, stream, in_hidden, h_f, hx);

  // ---- preamble GEMMs (M=1024, run once) ----
  {
    SrlGemmArgs g{};
    g.nOuts = 2;
    g.out[0] = mkOut(0, in_mk_b, nullptr, nullptr, 0, mk_h, 1024, 0, 0, 0);
    g.out[1] = mkOut(1024, in_mv_b, nullptr, nullptr, 0, mv_h, 1024, 0, 0, 0);
    runSm(1024, 2048, 1024, mem_h, 1024, wt_mem_kv, 1024, 1.f, g);
  }
  runS(1024, 1024, 1024, mk_h, 1024, wt_mattn_k, 1024, 1.f, in_mak_b, nullptr, nullptr, 0, mak_h, 1024, 0);
  runS(1024, 1024, 1024, mv_h, 1024, wt_mattn_v, 1024, 1.f, in_mav_b, nullptr, nullptr, 0, mavT_h, 0, 1);
  runS(1024, 1024, 1024, wmaq_t, 1024, mqw_nt, 1024, 1.f, nullptr, nullptr, nullptr, 0, wt_mq_comp, 1024, 0);

  float* h_out = (float*)d_out;
  const float kLog2e = 1.4426950408889634f;
  for (int step = 0; step < 3; ++step) {
    {  // fused rule-logits + Q + K + V projection: 128x128 pipelined, 896 blocks
      SrlGemmArgs g{};
      g.nOuts = 4;
      g.out[0] = mkOut(0,    bias_qkvr,        nullptr, logits_f, 512, nullptr, 0, 0, 0, 0);
      g.out[1] = mkOut(512,  bias_qkvr + 512,  nullptr, nullptr, 0, q_h, 1024, 0, 0, 0);
      g.out[2] = mkOut(1536, bias_qkvr + 1536, nullptr, nullptr, 0, k_h, 1024, 0, 0, 0);
      g.out[3] = mkOut(2560, bias_qkvr + 2560, nullptr, nullptr, 0, vT_h, 0, 1, 0, 0);
      runP(4096, 3584, 1024, hx, 2048, wt_qkvr, 1024, 1.f, g);
    }
    hipLaunchKernelGGL(srl_softmax_rule, dim3(4096), dim3(256), 0, stream, logits_f, probs_h);
    runS(4096, 1024, 512, probs_h, 512, wt_remb, 512, 1.f, nullptr, nullptr, nullptr, 0, hx + 1024, 2048, 0);
    {
      SrlFlashArgs fa;
      fa.Q = q_h; fa.K = k_h; fa.VT = vT_h; fa.O = ctx_h;
      fa.sQb = 1048576; fa.sKb = 1048576; fa.sVb = 1048576; fa.scale = 0.125f * kLog2e;
      hipLaunchKernelGGL(srl_flash, dim3(512), dim3(256), 0, stream, fa);
    }
    runS(4096, 1024, 1024, ctx_h, 1024, wt_attn_o, 1024, 1.f, in_attn_bo, h_f, h_f, 1024, hx, 2048, 0);
    runS(4096, 1024, 1024, hx, 2048, wt_mq_comp, 1024, 1.f, bcomp, nullptr, nullptr, 0, k_h, 1024, 0);
    {
      SrlFlashArgs fa;
      fa.Q = k_h; fa.K = mak_h; fa.VT = mavT_h; fa.O = ctx_h;
      fa.sQb = 1048576; fa.sKb = 0; fa.sVb = 0; fa.scale = 0.125f * kLog2e;
      hipLaunchKernelGGL(srl_flash, dim3(512), dim3(256), 0, stream, fa);
    }
    runS(4096, 1024, 1024, ctx_h, 1024, wt_mattn_o, 1024, 1.f, in_mao_b, h_f, h_f, 1024, hx, 2048, 0);
    runS(4096, 1024, 2048, hx, 2048, wt_ra1, 2048, 1.f, in_ra_b1, nullptr, ra1_f, 1024, nullptr, 0, 0);
    hipLaunchKernelGGL(srl_ln_gelu, dim3(4096), dim3(256), 0, stream, ra1_f, in_ln_s, in_ln_b, u_h);
    if (step < 2) {
      runS(4096, 1024, 1024, u_h, 1024, wt_ra2, 1024, 1.f, in_ra_b2, h_f, h_f, 1024, hx, 2048, 0);
    } else {
      // final step: write h directly into d_out (skips the 33.6MB finalize copy) and skip
      // the unconsumed hx write (8.4MB). Same fp32 values as before — purely traffic removal.
      runS(4096, 1024, 1024, u_h, 1024, wt_ra2, 1024, 1.f, in_ra_b2, h_f, h_out, 1024, nullptr, 0, 0);
    }
  }

  hipLaunchKernelGGL(srl_conf, dim3(1024), dim3(256), 0, stream, h_out, in_conf_w, in_conf_b,
                     h_out + 4194304);
}